// Round 7
// baseline (294.578 us; speedup 1.0000x reference)
//
#include <hip/hip_runtime.h>
#include <math.h>

#define NGRAPH 64
#define SCAN_BLK 1024

typedef short short8 __attribute__((ext_vector_type(8)));
typedef float floatx4 __attribute__((ext_vector_type(4)));
typedef unsigned uintx4 __attribute__((ext_vector_type(4)));

__device__ inline unsigned pack_bf16x2(float a, float b) {
    unsigned ua = __float_as_uint(a);
    unsigned ub = __float_as_uint(b);
    ua = (ua + 0x7fffu + ((ua >> 16) & 1u)) >> 16;   // RNE
    ub = (ub + 0x7fffu + ((ub >> 16) & 1u)) >> 16;
    return ua | (ub << 16);
}
__device__ inline unsigned short bf16_1(float a) {
    unsigned ua = __float_as_uint(a);
    return (unsigned short)((ua + 0x7fffu + ((ua >> 16) & 1u)) >> 16);
}
__device__ inline float bf16lo(unsigned u) { return __uint_as_float(u << 16); }
__device__ inline float bf16hi(unsigned u) { return __uint_as_float(u & 0xffff0000u); }

// order-preserving float->uint key (monotone); uint 0 is below every real key -> memset-0 identity
__device__ inline unsigned fkey(float v) {
    unsigned u = __float_as_uint(v);
    return (v >= 0.f) ? (u | 0x80000000u) : ~u;
}

// All 128-wide bf16 intermediates use QUARTER-MAJOR layout: [4][N][32] bf16.
// Quarter q of node n lives at ((size_t)q * N + n) * 32 .. +31 (3.2 MB slice).
// Agg kernels use XCD-affinity swizzle: blocks land on XCD (bid%8); quarter = (bid%8)>>1,
// so each XCD pair owns ONE quarter -> 3.2 MB working set fits the XCD's 4 MB L2.
// Gathers use nontemporal loads: zero reuse in 32KB L1, avoid 128B line-fill amplification.

// ---------------- fused: W2/W3 transpose+bf16-pack (blocks 0..31) + degree count (rest) ----------------

__global__ void pack_count(const int* __restrict__ dst, int E, int* __restrict__ cnt,
                           const float* __restrict__ W2, const float* __restrict__ W3,
                           unsigned* __restrict__ Wt2, unsigned* __restrict__ Wt3) {
    if (blockIdx.x < 32) {
        int b = blockIdx.x;
        const float* W = (b < 16) ? W2 : W3;
        unsigned* Wt = (b < 16) ? Wt2 : Wt3;
        b &= 15;
        int bk = b & 3, bn = b >> 2;
        __shared__ float s[32][33];
        int tx = threadIdx.x & 31, ty = threadIdx.x >> 5;
#pragma unroll
        for (int r = 0; r < 4; ++r)
            s[r * 8 + ty][tx] = W[(bk * 32 + r * 8 + ty) * 128 + bn * 32 + tx];
        __syncthreads();
        int t16 = threadIdx.x & 15, tn = threadIdx.x >> 4;
#pragma unroll
        for (int pass = 0; pass < 2; ++pass) {
            int nl = pass * 16 + tn;
            unsigned pk = pack_bf16x2(s[2 * t16][nl], s[2 * t16 + 1][nl]);
            Wt[(bn * 32 + nl) * 64 + bk * 16 + t16] = pk;
        }
    } else {
        int e = (blockIdx.x - 32) * blockDim.x + threadIdx.x;
        if (e < E) atomicAdd(&cnt[dst[e]], 1);
    }
}

// ---- fused scan: per-block exclusive scan + last-block closes (block-offset scan + goff) ----
// Consumers compute final row_ptr as row_ptr[i] + bsum[i>>10] on the fly.

__global__ __launch_bounds__(SCAN_BLK) void scanA(const int* __restrict__ cnt,
                                                  const float* __restrict__ x,
                                                  int* __restrict__ row_ptr,
                                                  int* __restrict__ bsum,
                                                  float* __restrict__ dinv,
                                                  float2* __restrict__ y,
                                                  const int* __restrict__ batch,
                                                  int* __restrict__ ticket,
                                                  int* __restrict__ goff, int N) {
    __shared__ int sm[SCAN_BLK];
    __shared__ int amLast;
    int i = blockIdx.x * SCAN_BLK + threadIdx.x;
    int v = (i < N) ? cnt[i] : 0;
    if (i < N) {
        float dv = rsqrtf((float)v + 1.0f);
        dinv[i] = dv;
        float2 xv = ((const float2*)x)[i];
        y[i] = make_float2(xv.x * dv, xv.y * dv);
    }
    sm[threadIdx.x] = v;
    __syncthreads();
    for (int off = 1; off < SCAN_BLK; off <<= 1) {
        int t = (threadIdx.x >= (unsigned)off) ? sm[threadIdx.x - off] : 0;
        __syncthreads();
        sm[threadIdx.x] += t;
        __syncthreads();
    }
    if (i < N) row_ptr[i] = sm[threadIdx.x] - v;
    if (threadIdx.x == SCAN_BLK - 1) bsum[blockIdx.x] = sm[SCAN_BLK - 1];
    __syncthreads();                       // all block stores issued & drained
    if (threadIdx.x == 0) {
        __threadfence();                   // publish this block's stores device-wide
        amLast = (atomicAdd(ticket, 1) == (int)gridDim.x - 1);
    }
    __syncthreads();
    if (!amLast) return;
    // closer block: exclusive-scan the block sums (coherent atomic reads), compute goff
    int nb = (int)gridDim.x;
    int v2 = (threadIdx.x < (unsigned)nb) ? atomicAdd(&bsum[threadIdx.x], 0) : 0;
    sm[threadIdx.x] = v2;
    __syncthreads();
    for (int off = 1; off < SCAN_BLK; off <<= 1) {
        int t = (threadIdx.x >= (unsigned)off) ? sm[threadIdx.x - off] : 0;
        __syncthreads();
        sm[threadIdx.x] += t;
        __syncthreads();
    }
    if (threadIdx.x < (unsigned)nb) bsum[threadIdx.x] = sm[threadIdx.x] - v2;
    if (threadIdx.x <= NGRAPH) {
        int g = threadIdx.x;
        int lo = 0, hi = N;
        while (lo < hi) {
            int mid = (lo + hi) >> 1;
            if (batch[mid] < g) lo = mid + 1; else hi = mid;
        }
        goff[g] = lo;
    }
}

// reverse-fill using cnt itself (dead after scan); applies block offset on the fly
__global__ void fill_kernel(const int* __restrict__ src, const int* __restrict__ dst, int E,
                            const int* __restrict__ row_ptr, const int* __restrict__ bsum,
                            int* __restrict__ cnt, int* __restrict__ col) {
    int e = blockIdx.x * blockDim.x + threadIdx.x;
    if (e < E) {
        int d = dst[e];
        int base = row_ptr[d] + bsum[d >> 10];
        int p = base + atomicSub(&cnt[d], 1) - 1;
        col[p] = src[e];
    }
}

// ---------------- layer 1 fused: z = agg(y) ; h1 = tanh(z @ W1 + b1) (bf16, quarter-major out) --------

__global__ __launch_bounds__(256) void agg_x_t1(const float2* __restrict__ y,
                                                const int* __restrict__ row_ptr,
                                                const int* __restrict__ bsum,
                                                const int* __restrict__ col,
                                                const float* __restrict__ dinv,
                                                const float* __restrict__ W1,
                                                const float* __restrict__ b1,
                                                unsigned short* __restrict__ h, int N, int E) {
    __shared__ float4 sW[64];     // W1[2][128]
    __shared__ float4 sb[32];     // b1[128]
    __shared__ float2 zs[256];
    if (threadIdx.x < 64) sW[threadIdx.x] = ((const float4*)W1)[threadIdx.x];
    if (threadIdx.x < 32) sb[threadIdx.x] = ((const float4*)b1)[threadIdx.x];

    int v = blockIdx.x * 256 + threadIdx.x;
    float2 zv = make_float2(0.f, 0.f);
    if (v < N) {
        int s = row_ptr[v] + bsum[v >> 10];
        int e = (v + 1 < N) ? row_ptr[v + 1] + bsum[(v + 1) >> 10] : E;
        float2 a0 = y[v];
        float2 a1 = make_float2(0.f, 0.f);
        float2 a2 = make_float2(0.f, 0.f);
        float2 a3 = make_float2(0.f, 0.f);
        int j = s;
        for (; j + 4 <= e; j += 4) {
            int u0 = col[j], u1 = col[j + 1], u2 = col[j + 2], u3 = col[j + 3];
            float2 v0 = y[u0], v1 = y[u1], v2 = y[u2], v3 = y[u3];
            a0.x += v0.x; a0.y += v0.y;
            a1.x += v1.x; a1.y += v1.y;
            a2.x += v2.x; a2.y += v2.y;
            a3.x += v3.x; a3.y += v3.y;
        }
        for (; j < e; ++j) {
            float2 vv = y[col[j]];
            a0.x += vv.x; a0.y += vv.y;
        }
        float dv = dinv[v];
        zv = make_float2(dv * (a0.x + a1.x + a2.x + a3.x),
                         dv * (a0.y + a1.y + a2.y + a3.y));
    }
    zs[threadIdx.x] = zv;
    __syncthreads();

    int q = threadIdx.x & 31;          // col quad (4 cols)
    int rsub = threadIdx.x >> 5;       // 0..7
    float4 w0 = sW[q];
    float4 w1 = sW[32 + q];
    float4 b = sb[q];
    size_t qoff = (size_t)(q >> 3) * N;  // quarter base (rows)
#pragma unroll 4
    for (int pass = 0; pass < 32; ++pass) {
        int local = pass * 8 + rsub;
        int row = blockIdx.x * 256 + local;
        if (row >= N) break;
        float2 z = zs[local];
        float ox = tanhf(fmaf(z.x, w0.x, fmaf(z.y, w1.x, b.x)));
        float oy = tanhf(fmaf(z.x, w0.y, fmaf(z.y, w1.y, b.y)));
        float oz = tanhf(fmaf(z.x, w0.z, fmaf(z.y, w1.z, b.z)));
        float ow = tanhf(fmaf(z.x, w0.w, fmaf(z.y, w1.w, b.w)));
        uint2 pk;
        pk.x = pack_bf16x2(ox, oy);
        pk.y = pack_bf16x2(oz, ow);
        ((uint2*)h)[(qoff + row) * 8 + (q & 7)] = pk;
    }
}

// ---------------- MFMA GEMM: t[4][N][32](bf16) = (A[4][N][32](bf16) @ W) * dinv ----------------
// Operands SWAPPED vs naive: mfma(W_frag, A_frag, acc) computes the transposed fragment, so
// lane&15 indexes the NODE and reg 0..3 indexes 4 consecutive features -> 8B uint2 stores.

__global__ __launch_bounds__(256) void gemm_mfma(const unsigned short* __restrict__ A,
                                                 const unsigned* __restrict__ Wt,
                                                 const float* __restrict__ dinv,
                                                 unsigned short* __restrict__ t, int N) {
    __shared__ unsigned sW[128 * 68];
    const uint4* Wt4 = (const uint4*)Wt;
    for (int i = threadIdx.x; i < 2048; i += 256) {
        int n = i >> 4, c = i & 15;
        *(uint4*)&sW[n * 68 + c * 4] = Wt4[i];
    }
    __syncthreads();
    int l = threadIdx.x & 63;
    int w = threadIdx.x >> 6;
    int lm = l & 15;
    int q4 = l >> 4;

    floatx4 acc[2][8];
#pragma unroll
    for (int i = 0; i < 2; ++i)
#pragma unroll
        for (int j = 0; j < 8; ++j) acc[i][j] = (floatx4){0.f, 0.f, 0.f, 0.f};

    int rowbase = blockIdx.x * 128 + w * 32;
    int k8 = q4 * 8;
#pragma unroll
    for (int ks = 0; ks < 4; ++ks) {
        // A element [r][ks*32 + k8 ..] lives in quarter ks at offset k8
        short8 a[2];
#pragma unroll
        for (int mt = 0; mt < 2; ++mt) {
            int r = min(rowbase + mt * 16 + lm, N - 1);
            a[mt] = *(const short8*)(A + ((size_t)ks * N + r) * 32 + k8);
        }
#pragma unroll
        for (int nt = 0; nt < 8; ++nt) {
            short8 b = *(const short8*)&sW[(nt * 16 + lm) * 68 + ks * 16 + q4 * 4];
#pragma unroll
            for (int mt = 0; mt < 2; ++mt)
                acc[mt][nt] = __builtin_amdgcn_mfma_f32_16x16x32_bf16(b, a[mt], acc[mt][nt], 0, 0, 0);
        }
    }

    // D fragment (swapped): node = lane&15 (per mt tile), feature = nt*16 + q4*4 + reg
#pragma unroll
    for (int mt = 0; mt < 2; ++mt) {
        int gr = rowbase + mt * 16 + lm;
        if (gr < N) {
            float dv = dinv[gr];
#pragma unroll
            for (int nt = 0; nt < 8; ++nt) {
                uint2 pk;
                pk.x = pack_bf16x2(acc[mt][nt][0] * dv, acc[mt][nt][1] * dv);
                pk.y = pack_bf16x2(acc[mt][nt][2] * dv, acc[mt][nt][3] * dv);
                *(uint2*)(t + ((size_t)(nt >> 1) * N + gr) * 32 + (nt & 1) * 16 + q4 * 4) = pk;
            }
        }
    }
}

// ---------------- layer-2 aggregation: 256 nodes/block (1024 thr), 4 lanes/node -------------
// XCD-affinity swizzle: quarter = (bid%8)>>1, chunk = (bid>>3)*2 + (bid&1).
// Each XCD pair works one quarter -> 3.2 MB gather table resident in that XCD's 4 MB L2.
// Gathers nontemporal (L1 bypass).

__global__ __launch_bounds__(1024) void agg_kernel(const unsigned short* __restrict__ t,
                                                   const int* __restrict__ row_ptr,
                                                   const int* __restrict__ bsum,
                                                   const int* __restrict__ col,
                                                   const float* __restrict__ dinv,
                                                   const float* __restrict__ bias,
                                                   unsigned short* __restrict__ out, int N, int E) {
    int nchunk = (N + 255) >> 8;
    int bid = (int)blockIdx.x;
    int r8 = bid & 7;
    int qt = r8 >> 1;                              // feature quarter 0..3 (XCD pair)
    int c = (bid >> 3) * 2 + (r8 & 1);             // node chunk
    if (c >= nchunk) return;
    int q = threadIdx.x & 3;                       // 16B col slot (8 bf16)
    int node = c * 256 + ((int)threadIdx.x >> 2);
    if (node >= N) return;
    const uintx4* t4 = (const uintx4*)t;
    unsigned qb = (unsigned)qt * (unsigned)N;
    int s = row_ptr[node] + bsum[node >> 10];
    int e = (node + 1 < N) ? row_ptr[node + 1] + bsum[(node + 1) >> 10] : E;
    int deg = e - s;

    float a[8];
    {   // self term
        uintx4 v = __builtin_nontemporal_load(&t4[(size_t)((qb + (unsigned)node) * 4u + q)]);
        a[0] = bf16lo(v.x); a[1] = bf16hi(v.x);
        a[2] = bf16lo(v.y); a[3] = bf16hi(v.y);
        a[4] = bf16lo(v.z); a[5] = bf16hi(v.z);
        a[6] = bf16lo(v.w); a[7] = bf16hi(v.w);
    }
    int j = 0;
    for (; j + 4 <= deg; j += 4) {
        int u0 = col[s + j];
        int u1 = col[s + j + 1];
        int u2 = col[s + j + 2];
        int u3 = col[s + j + 3];
        uintx4 v0 = __builtin_nontemporal_load(&t4[(size_t)((qb + (unsigned)u0) * 4u + q)]);
        uintx4 v1 = __builtin_nontemporal_load(&t4[(size_t)((qb + (unsigned)u1) * 4u + q)]);
        uintx4 v2 = __builtin_nontemporal_load(&t4[(size_t)((qb + (unsigned)u2) * 4u + q)]);
        uintx4 v3 = __builtin_nontemporal_load(&t4[(size_t)((qb + (unsigned)u3) * 4u + q)]);
        a[0] += bf16lo(v0.x); a[1] += bf16hi(v0.x);
        a[2] += bf16lo(v0.y); a[3] += bf16hi(v0.y);
        a[4] += bf16lo(v0.z); a[5] += bf16hi(v0.z);
        a[6] += bf16lo(v0.w); a[7] += bf16hi(v0.w);
        a[0] += bf16lo(v1.x); a[1] += bf16hi(v1.x);
        a[2] += bf16lo(v1.y); a[3] += bf16hi(v1.y);
        a[4] += bf16lo(v1.z); a[5] += bf16hi(v1.z);
        a[6] += bf16lo(v1.w); a[7] += bf16hi(v1.w);
        a[0] += bf16lo(v2.x); a[1] += bf16hi(v2.x);
        a[2] += bf16lo(v2.y); a[3] += bf16hi(v2.y);
        a[4] += bf16lo(v2.z); a[5] += bf16hi(v2.z);
        a[6] += bf16lo(v2.w); a[7] += bf16hi(v2.w);
        a[0] += bf16lo(v3.x); a[1] += bf16hi(v3.x);
        a[2] += bf16lo(v3.y); a[3] += bf16hi(v3.y);
        a[4] += bf16lo(v3.z); a[5] += bf16hi(v3.z);
        a[6] += bf16lo(v3.w); a[7] += bf16hi(v3.w);
    }
    for (; j < deg; ++j) {
        int u = col[s + j];
        uintx4 v = __builtin_nontemporal_load(&t4[(size_t)((qb + (unsigned)u) * 4u + q)]);
        a[0] += bf16lo(v.x); a[1] += bf16hi(v.x);
        a[2] += bf16lo(v.y); a[3] += bf16hi(v.y);
        a[4] += bf16lo(v.z); a[5] += bf16hi(v.z);
        a[6] += bf16lo(v.w); a[7] += bf16hi(v.w);
    }

    float dv = dinv[node];
    const float4* b4 = (const float4*)bias;
    float4 b0 = b4[qt * 8 + q * 2];
    float4 b1 = b4[qt * 8 + q * 2 + 1];
    uint4 pk;
    pk.x = pack_bf16x2(tanhf(fmaf(dv, a[0], b0.x)), tanhf(fmaf(dv, a[1], b0.y)));
    pk.y = pack_bf16x2(tanhf(fmaf(dv, a[2], b0.z)), tanhf(fmaf(dv, a[3], b0.w)));
    pk.z = pack_bf16x2(tanhf(fmaf(dv, a[4], b1.x)), tanhf(fmaf(dv, a[5], b1.y)));
    pk.w = pack_bf16x2(tanhf(fmaf(dv, a[6], b1.z)), tanhf(fmaf(dv, a[7], b1.w)));
    ((uint4*)out)[(size_t)((qb + (unsigned)node) * 4u + q)] = pk;
}

// ---------------- layer-3 aggregation + FUSED pooling (h3 never materialized) ----------------
// Same XCD-affinity swizzle + nontemporal gathers. Per node: fp32 tanh outputs in-register;
// wave-butterfly max/sum when the wave's 16 nodes share a graph, merge via LDS, 128 atomics/block.

__global__ __launch_bounds__(1024) void agg3_pool(const unsigned short* __restrict__ t,
                                                  const int* __restrict__ row_ptr,
                                                  const int* __restrict__ bsum,
                                                  const int* __restrict__ col,
                                                  const float* __restrict__ dinv,
                                                  const float* __restrict__ bias,
                                                  const int* __restrict__ batch,
                                                  unsigned* __restrict__ pmax,
                                                  float* __restrict__ psum, int N, int E) {
    int nchunk = (N + 255) >> 8;
    int bid = (int)blockIdx.x;
    int r8 = bid & 7;
    int qt = r8 >> 1;
    int c = (bid >> 3) * 2 + (r8 & 1);
    if (c >= nchunk) return;

    __shared__ unsigned smax[2][32];
    __shared__ float ssum[2][32];
    if (threadIdx.x < 64) {
        smax[threadIdx.x >> 5][threadIdx.x & 31] = 0u;
        ssum[threadIdx.x >> 5][threadIdx.x & 31] = 0.f;
    }
    __syncthreads();

    int q = threadIdx.x & 3;
    int blockBase = c * 256;
    int node = blockBase + ((int)threadIdx.x >> 2);
    bool valid = node < N;
    int nc = valid ? node : N - 1;
    const uintx4* t4 = (const uintx4*)t;
    unsigned qb = (unsigned)qt * (unsigned)N;
    int s = row_ptr[nc] + bsum[nc >> 10];
    int e = (nc + 1 < N) ? row_ptr[nc + 1] + bsum[(nc + 1) >> 10] : E;
    int deg = valid ? (e - s) : 0;

    float a[8];
    {   // self term (of nc; discarded for invalid lanes)
        uintx4 v = __builtin_nontemporal_load(&t4[(size_t)((qb + (unsigned)nc) * 4u + q)]);
        a[0] = bf16lo(v.x); a[1] = bf16hi(v.x);
        a[2] = bf16lo(v.y); a[3] = bf16hi(v.y);
        a[4] = bf16lo(v.z); a[5] = bf16hi(v.z);
        a[6] = bf16lo(v.w); a[7] = bf16hi(v.w);
    }
    int j = 0;
    for (; j + 4 <= deg; j += 4) {
        int u0 = col[s + j];
        int u1 = col[s + j + 1];
        int u2 = col[s + j + 2];
        int u3 = col[s + j + 3];
        uintx4 v0 = __builtin_nontemporal_load(&t4[(size_t)((qb + (unsigned)u0) * 4u + q)]);
        uintx4 v1 = __builtin_nontemporal_load(&t4[(size_t)((qb + (unsigned)u1) * 4u + q)]);
        uintx4 v2 = __builtin_nontemporal_load(&t4[(size_t)((qb + (unsigned)u2) * 4u + q)]);
        uintx4 v3 = __builtin_nontemporal_load(&t4[(size_t)((qb + (unsigned)u3) * 4u + q)]);
        a[0] += bf16lo(v0.x); a[1] += bf16hi(v0.x);
        a[2] += bf16lo(v0.y); a[3] += bf16hi(v0.y);
        a[4] += bf16lo(v0.z); a[5] += bf16hi(v0.z);
        a[6] += bf16lo(v0.w); a[7] += bf16hi(v0.w);
        a[0] += bf16lo(v1.x); a[1] += bf16hi(v1.x);
        a[2] += bf16lo(v1.y); a[3] += bf16hi(v1.y);
        a[4] += bf16lo(v1.z); a[5] += bf16hi(v1.z);
        a[6] += bf16lo(v1.w); a[7] += bf16hi(v1.w);
        a[0] += bf16lo(v2.x); a[1] += bf16hi(v2.x);
        a[2] += bf16lo(v2.y); a[3] += bf16hi(v2.y);
        a[4] += bf16lo(v2.z); a[5] += bf16hi(v2.z);
        a[6] += bf16lo(v2.w); a[7] += bf16hi(v2.w);
        a[0] += bf16lo(v3.x); a[1] += bf16hi(v3.x);
        a[2] += bf16lo(v3.y); a[3] += bf16hi(v3.y);
        a[4] += bf16lo(v3.z); a[5] += bf16hi(v3.z);
        a[6] += bf16lo(v3.w); a[7] += bf16hi(v3.w);
    }
    for (; j < deg; ++j) {
        int u = col[s + j];
        uintx4 v = __builtin_nontemporal_load(&t4[(size_t)((qb + (unsigned)u) * 4u + q)]);
        a[0] += bf16lo(v.x); a[1] += bf16hi(v.x);
        a[2] += bf16lo(v.y); a[3] += bf16hi(v.y);
        a[4] += bf16lo(v.z); a[5] += bf16hi(v.z);
        a[6] += bf16lo(v.w); a[7] += bf16hi(v.w);
    }

    float dv = dinv[nc];
    const float4* b4 = (const float4*)bias;
    float4 b0 = b4[qt * 8 + q * 2];
    float4 b1 = b4[qt * 8 + q * 2 + 1];
    float o[8];
    o[0] = tanhf(fmaf(dv, a[0], b0.x)); o[1] = tanhf(fmaf(dv, a[1], b0.y));
    o[2] = tanhf(fmaf(dv, a[2], b0.z)); o[3] = tanhf(fmaf(dv, a[3], b0.w));
    o[4] = tanhf(fmaf(dv, a[4], b1.x)); o[5] = tanhf(fmaf(dv, a[5], b1.y));
    o[6] = tanhf(fmaf(dv, a[6], b1.z)); o[7] = tanhf(fmaf(dv, a[7], b1.w));

    int g = batch[nc];
    int g0 = batch[min(blockBase, N - 1)];
    int gl = __shfl(g, 0, 64);
    int gh = __shfl(g, 63, 64);

    if (gl == gh) {
        // fast path: whole wave in one graph -> butterfly reduce over the 16 node groups
        float m[8], sv[8];
#pragma unroll
        for (int k = 0; k < 8; ++k) {
            m[k] = valid ? o[k] : -3.402823466e+38f;
            sv[k] = valid ? o[k] : 0.f;
        }
#pragma unroll
        for (int st = 4; st < 64; st <<= 1) {
#pragma unroll
            for (int k = 0; k < 8; ++k) {
                m[k] = fmaxf(m[k], __shfl_xor(m[k], st, 64));
                sv[k] += __shfl_xor(sv[k], st, 64);
            }
        }
        if (((threadIdx.x & 63) >> 2) == 0) {   // 4 lanes (q=0..3) hold reduced values
            int seg = gl - g0;
            if (seg < 2) {
#pragma unroll
                for (int k = 0; k < 8; ++k) {
                    atomicMax(&smax[seg][q * 8 + k], fkey(m[k]));
                    atomicAdd(&ssum[seg][q * 8 + k], sv[k]);
                }
            } else {                            // safety net (tiny graphs)
#pragma unroll
                for (int k = 0; k < 8; ++k) {
                    atomicMax(&pmax[gl * 128 + qt * 32 + q * 8 + k], fkey(m[k]));
                    atomicAdd(&psum[gl * 128 + qt * 32 + q * 8 + k], sv[k]);
                }
            }
        }
    } else {
        // boundary wave: per-lane merge
        if (valid) {
            int seg = g - g0;
            if (seg < 2) {
#pragma unroll
                for (int k = 0; k < 8; ++k) {
                    atomicMax(&smax[seg][q * 8 + k], fkey(o[k]));
                    atomicAdd(&ssum[seg][q * 8 + k], o[k]);
                }
            } else {
#pragma unroll
                for (int k = 0; k < 8; ++k) {
                    atomicMax(&pmax[g * 128 + qt * 32 + q * 8 + k], fkey(o[k]));
                    atomicAdd(&psum[g * 128 + qt * 32 + q * 8 + k], o[k]);
                }
            }
        }
    }
    __syncthreads();
    if (threadIdx.x < 64) {
        int seg = threadIdx.x >> 5, cc = threadIdx.x & 31;
        int g0b = batch[min(blockBase, N - 1)];
        int gg = g0b + seg;
        if (gg < NGRAPH) {
            atomicMax(&pmax[gg * 128 + qt * 32 + cc], smax[seg][cc]);
            atomicAdd(&psum[gg * 128 + qt * 32 + cc], ssum[seg][cc]);
        }
    }
}

// ---------------- final: decode pooled accumulators + output head ----------------

__global__ __launch_bounds__(128) void pool_final(const unsigned* __restrict__ pmax,
                                                  const float* __restrict__ psum,
                                                  const int* __restrict__ goff,
                                                  const float* __restrict__ Wo,
                                                  const float* __restrict__ bo,
                                                  float* __restrict__ out) {
    __shared__ float p[256];
    int g = blockIdx.x;
    int j = threadIdx.x;
    int cnt = goff[g + 1] - goff[g];
    unsigned key = pmax[g * 128 + j];
    float mx = (key & 0x80000000u) ? __uint_as_float(key ^ 0x80000000u)
                                   : __uint_as_float(~key);
    p[j] = (cnt > 0) ? mx : 0.f;
    p[128 + j] = psum[g * 128 + j] / fmaxf((float)cnt, 1.f);
    __syncthreads();
    if (j < 41) {
        float acc = bo[j];
        for (int k = 0; k < 256; ++k) acc = fmaf(p[k], Wo[k * 41 + j], acc);
        out[g * 41 + j] = tanhf(acc);
    }
}

// ---------------- launch ----------------

extern "C" void kernel_launch(void* const* d_in, const int* in_sizes, int n_in,
                              void* d_out, int out_size, void* d_ws, size_t ws_size,
                              hipStream_t stream) {
    const float* x   = (const float*)d_in[0];
    const int*   ei  = (const int*)d_in[1];
    const int* batch = (const int*)d_in[2];
    const float* W1  = (const float*)d_in[3];
    const float* b1  = (const float*)d_in[4];
    const float* W2  = (const float*)d_in[5];
    const float* b2  = (const float*)d_in[6];
    const float* W3  = (const float*)d_in[7];
    const float* b3  = (const float*)d_in[8];
    const float* Wo  = (const float*)d_in[9];
    const float* bo  = (const float*)d_in[10];
    float* outp = (float*)d_out;

    int N = in_sizes[2];
    int E = in_sizes[1] / 2;
    const int* src = ei;
    const int* dst = ei + E;

    char* p = (char*)d_ws;
    auto alloc = [&](size_t bytes) -> char* {
        char* q = p;
        p += (bytes + 255) & ~(size_t)255;
        return q;
    };
    unsigned short* t   = (unsigned short*)alloc((size_t)N * 128 * 2);  // bf16 gemm out [4][N][32]
    unsigned short* hb  = (unsigned short*)alloc((size_t)N * 128 * 2);  // bf16 h1 / h2  [4][N][32]
    float* dinv   = (float*)alloc((size_t)N * 4);
    int*   rowp   = (int*)alloc((size_t)(N + 1) * 4);
    int*   col    = (int*)alloc((size_t)E * 4);
    int*   goff   = (int*)alloc(65 * 4);
    float2* y     = (float2*)alloc((size_t)N * 8);
    unsigned* Wt2 = (unsigned*)alloc(128 * 64 * 4);
    unsigned* Wt3 = (unsigned*)alloc(128 * 64 * 4);
    int nscan = (N + SCAN_BLK - 1) / SCAN_BLK;
    int*   bsum   = (int*)alloc((size_t)nscan * 4);
    // zero-init region: cnt | ticket | pmax | psum (single memset)
    size_t cntB = ((size_t)N * 4 + 255) & ~(size_t)255;
    char* zbase = alloc(cntB + 256 + NGRAPH * 128 * 4 * 2);
    int*      cnt  = (int*)zbase;
    int*      tick = (int*)(zbase + cntB);
    unsigned* pmax = (unsigned*)(zbase + cntB + 256);
    float*    psum = (float*)(zbase + cntB + 256 + NGRAPH * 128 * 4);

    (void)hipMemsetAsync(zbase, 0, cntB + 256 + NGRAPH * 128 * 4 * 2, stream);

    pack_count<<<32 + (E + 255) / 256, 256, 0, stream>>>(dst, E, cnt, W2, W3, Wt2, Wt3);
    scanA<<<nscan, SCAN_BLK, 0, stream>>>(cnt, x, rowp, bsum, dinv, y, batch, tick, goff, N);
    fill_kernel<<<(E + 255) / 256, 256, 0, stream>>>(src, dst, E, rowp, bsum, cnt, col);

    // agg grid: XCD-affinity swizzled flat grid (see agg_kernel)
    int nchunk = (N + 255) >> 8;
    int nchunkR = (nchunk + 1) & ~1;         // round up to even
    int nblk = nchunkR * 4;                  // = (nchunkR/2) * 8, multiple of 8

    // layer 1: fused agg(x) + transform -> h1 (bf16, quarter-major)
    agg_x_t1<<<(N + 255) / 256, 256, 0, stream>>>(y, rowp, bsum, col, dinv, W1, b1, hb, N, E);
    // layer 2
    gemm_mfma<<<(N + 127) / 128, 256, 0, stream>>>(hb, Wt2, dinv, t, N);
    agg_kernel<<<nblk, 1024, 0, stream>>>(t, rowp, bsum, col, dinv, b2, hb, N, E);
    // layer 3 (pooling fused into agg)
    gemm_mfma<<<(N + 127) / 128, 256, 0, stream>>>(hb, Wt3, dinv, t, N);
    agg3_pool<<<nblk, 1024, 0, stream>>>(t, rowp, bsum, col, dinv, b3, batch, pmax, psum, N, E);

    pool_final<<<NGRAPH, 128, 0, stream>>>(pmax, psum, goff, Wo, bo, outp);
}

// Round 8
// 261.305 us; speedup vs baseline: 1.1273x; 1.1273x over previous
//
#include <hip/hip_runtime.h>
#include <math.h>

#define NGRAPH 64
#define SCAN_BLK 1024

typedef short short8 __attribute__((ext_vector_type(8)));
typedef float floatx4 __attribute__((ext_vector_type(4)));

__device__ inline unsigned pack_bf16x2(float a, float b) {
    unsigned ua = __float_as_uint(a);
    unsigned ub = __float_as_uint(b);
    ua = (ua + 0x7fffu + ((ua >> 16) & 1u)) >> 16;   // RNE
    ub = (ub + 0x7fffu + ((ub >> 16) & 1u)) >> 16;
    return ua | (ub << 16);
}
__device__ inline unsigned short bf16_1(float a) {
    unsigned ua = __float_as_uint(a);
    return (unsigned short)((ua + 0x7fffu + ((ua >> 16) & 1u)) >> 16);
}
__device__ inline float bf16lo(unsigned u) { return __uint_as_float(u << 16); }
__device__ inline float bf16hi(unsigned u) { return __uint_as_float(u & 0xffff0000u); }

// order-preserving float->uint key (monotone); uint 0 is below every real key -> memset-0 identity
__device__ inline unsigned fkey(float v) {
    unsigned u = __float_as_uint(v);
    return (v >= 0.f) ? (u | 0x80000000u) : ~u;
}

// All 128-wide bf16 intermediates use QUARTER-MAJOR layout: [4][N][32] bf16.
// Quarter q of node n lives at ((size_t)q * N + n) * 32 .. +31 (3.2 MB slice).
// Agg kernels use XCD-affinity swizzle: blocks land on XCD (bid%8); quarter = (bid%8)>>1,
// so each XCD pair owns ONE quarter -> 3.2 MB working set fits the XCD's 4 MB L2.
// NOTE (r7 post-mortem): nontemporal loads on the gathers REGRESSED (+30us) — the nt flag
// evicts early from L2 too, destroying the XCD-L2 residency. Plain loads here.

// ---------------- fused: W2/W3 transpose+bf16-pack (blocks 0..31) + degree count (rest) ----------------

__global__ void pack_count(const int* __restrict__ dst, int E, int* __restrict__ cnt,
                           const float* __restrict__ W2, const float* __restrict__ W3,
                           unsigned* __restrict__ Wt2, unsigned* __restrict__ Wt3) {
    if (blockIdx.x < 32) {
        int b = blockIdx.x;
        const float* W = (b < 16) ? W2 : W3;
        unsigned* Wt = (b < 16) ? Wt2 : Wt3;
        b &= 15;
        int bk = b & 3, bn = b >> 2;
        __shared__ float s[32][33];
        int tx = threadIdx.x & 31, ty = threadIdx.x >> 5;
#pragma unroll
        for (int r = 0; r < 4; ++r)
            s[r * 8 + ty][tx] = W[(bk * 32 + r * 8 + ty) * 128 + bn * 32 + tx];
        __syncthreads();
        int t16 = threadIdx.x & 15, tn = threadIdx.x >> 4;
#pragma unroll
        for (int pass = 0; pass < 2; ++pass) {
            int nl = pass * 16 + tn;
            unsigned pk = pack_bf16x2(s[2 * t16][nl], s[2 * t16 + 1][nl]);
            Wt[(bn * 32 + nl) * 64 + bk * 16 + t16] = pk;
        }
    } else {
        int e = (blockIdx.x - 32) * blockDim.x + threadIdx.x;
        if (e < E) atomicAdd(&cnt[dst[e]], 1);
    }
}

// ---- fused scan: per-block exclusive scan + last-block closes (block-offset scan + goff) ----
// Consumers compute final row_ptr as row_ptr[i] + bsum[i>>10] on the fly.

__global__ __launch_bounds__(SCAN_BLK) void scanA(const int* __restrict__ cnt,
                                                  const float* __restrict__ x,
                                                  int* __restrict__ row_ptr,
                                                  int* __restrict__ bsum,
                                                  float* __restrict__ dinv,
                                                  float2* __restrict__ y,
                                                  const int* __restrict__ batch,
                                                  int* __restrict__ ticket,
                                                  int* __restrict__ goff, int N) {
    __shared__ int sm[SCAN_BLK];
    __shared__ int amLast;
    int i = blockIdx.x * SCAN_BLK + threadIdx.x;
    int v = (i < N) ? cnt[i] : 0;
    if (i < N) {
        float dv = rsqrtf((float)v + 1.0f);
        dinv[i] = dv;
        float2 xv = ((const float2*)x)[i];
        y[i] = make_float2(xv.x * dv, xv.y * dv);
    }
    sm[threadIdx.x] = v;
    __syncthreads();
    for (int off = 1; off < SCAN_BLK; off <<= 1) {
        int t = (threadIdx.x >= (unsigned)off) ? sm[threadIdx.x - off] : 0;
        __syncthreads();
        sm[threadIdx.x] += t;
        __syncthreads();
    }
    if (i < N) row_ptr[i] = sm[threadIdx.x] - v;
    if (threadIdx.x == SCAN_BLK - 1) bsum[blockIdx.x] = sm[SCAN_BLK - 1];
    __syncthreads();                       // all block stores issued & drained
    if (threadIdx.x == 0) {
        __threadfence();                   // publish this block's stores device-wide
        amLast = (atomicAdd(ticket, 1) == (int)gridDim.x - 1);
    }
    __syncthreads();
    if (!amLast) return;
    // closer block: exclusive-scan the block sums (coherent atomic reads), compute goff
    int nb = (int)gridDim.x;
    int v2 = (threadIdx.x < (unsigned)nb) ? atomicAdd(&bsum[threadIdx.x], 0) : 0;
    sm[threadIdx.x] = v2;
    __syncthreads();
    for (int off = 1; off < SCAN_BLK; off <<= 1) {
        int t = (threadIdx.x >= (unsigned)off) ? sm[threadIdx.x - off] : 0;
        __syncthreads();
        sm[threadIdx.x] += t;
        __syncthreads();
    }
    if (threadIdx.x < (unsigned)nb) bsum[threadIdx.x] = sm[threadIdx.x] - v2;
    if (threadIdx.x <= NGRAPH) {
        int g = threadIdx.x;
        int lo = 0, hi = N;
        while (lo < hi) {
            int mid = (lo + hi) >> 1;
            if (batch[mid] < g) lo = mid + 1; else hi = mid;
        }
        goff[g] = lo;
    }
}

// reverse-fill using cnt itself (dead after scan); applies block offset on the fly
__global__ void fill_kernel(const int* __restrict__ src, const int* __restrict__ dst, int E,
                            const int* __restrict__ row_ptr, const int* __restrict__ bsum,
                            int* __restrict__ cnt, int* __restrict__ col) {
    int e = blockIdx.x * blockDim.x + threadIdx.x;
    if (e < E) {
        int d = dst[e];
        int base = row_ptr[d] + bsum[d >> 10];
        int p = base + atomicSub(&cnt[d], 1) - 1;
        col[p] = src[e];
    }
}

// ---------------- layer 1 fused: z = agg(y) ; h1 = tanh(z @ W1 + b1) (bf16, quarter-major out) --------

__global__ __launch_bounds__(256) void agg_x_t1(const float2* __restrict__ y,
                                                const int* __restrict__ row_ptr,
                                                const int* __restrict__ bsum,
                                                const int* __restrict__ col,
                                                const float* __restrict__ dinv,
                                                const float* __restrict__ W1,
                                                const float* __restrict__ b1,
                                                unsigned short* __restrict__ h, int N, int E) {
    __shared__ float4 sW[64];     // W1[2][128]
    __shared__ float4 sb[32];     // b1[128]
    __shared__ float2 zs[256];
    if (threadIdx.x < 64) sW[threadIdx.x] = ((const float4*)W1)[threadIdx.x];
    if (threadIdx.x < 32) sb[threadIdx.x] = ((const float4*)b1)[threadIdx.x];

    int v = blockIdx.x * 256 + threadIdx.x;
    float2 zv = make_float2(0.f, 0.f);
    if (v < N) {
        int s = row_ptr[v] + bsum[v >> 10];
        int e = (v + 1 < N) ? row_ptr[v + 1] + bsum[(v + 1) >> 10] : E;
        float2 a0 = y[v];
        float2 a1 = make_float2(0.f, 0.f);
        float2 a2 = make_float2(0.f, 0.f);
        float2 a3 = make_float2(0.f, 0.f);
        int j = s;
        for (; j + 4 <= e; j += 4) {
            int u0 = col[j], u1 = col[j + 1], u2 = col[j + 2], u3 = col[j + 3];
            float2 v0 = y[u0], v1 = y[u1], v2 = y[u2], v3 = y[u3];
            a0.x += v0.x; a0.y += v0.y;
            a1.x += v1.x; a1.y += v1.y;
            a2.x += v2.x; a2.y += v2.y;
            a3.x += v3.x; a3.y += v3.y;
        }
        for (; j < e; ++j) {
            float2 vv = y[col[j]];
            a0.x += vv.x; a0.y += vv.y;
        }
        float dv = dinv[v];
        zv = make_float2(dv * (a0.x + a1.x + a2.x + a3.x),
                         dv * (a0.y + a1.y + a2.y + a3.y));
    }
    zs[threadIdx.x] = zv;
    __syncthreads();

    int q = threadIdx.x & 31;          // col quad (4 cols)
    int rsub = threadIdx.x >> 5;       // 0..7
    float4 w0 = sW[q];
    float4 w1 = sW[32 + q];
    float4 b = sb[q];
    size_t qoff = (size_t)(q >> 3) * N;  // quarter base (rows)
#pragma unroll 4
    for (int pass = 0; pass < 32; ++pass) {
        int local = pass * 8 + rsub;
        int row = blockIdx.x * 256 + local;
        if (row >= N) break;
        float2 z = zs[local];
        float ox = tanhf(fmaf(z.x, w0.x, fmaf(z.y, w1.x, b.x)));
        float oy = tanhf(fmaf(z.x, w0.y, fmaf(z.y, w1.y, b.y)));
        float oz = tanhf(fmaf(z.x, w0.z, fmaf(z.y, w1.z, b.z)));
        float ow = tanhf(fmaf(z.x, w0.w, fmaf(z.y, w1.w, b.w)));
        uint2 pk;
        pk.x = pack_bf16x2(ox, oy);
        pk.y = pack_bf16x2(oz, ow);
        ((uint2*)h)[(qoff + row) * 8 + (q & 7)] = pk;
    }
}

// ---------------- MFMA GEMM: t[4][N][32](bf16) = (A[4][N][32](bf16) @ W) * dinv ----------------
// Operands SWAPPED vs naive: mfma(W_frag, A_frag, acc) computes the transposed fragment, so
// lane&15 indexes the NODE and reg 0..3 indexes 4 consecutive features -> 8B uint2 stores.

__global__ __launch_bounds__(256) void gemm_mfma(const unsigned short* __restrict__ A,
                                                 const unsigned* __restrict__ Wt,
                                                 const float* __restrict__ dinv,
                                                 unsigned short* __restrict__ t, int N) {
    __shared__ unsigned sW[128 * 68];
    const uint4* Wt4 = (const uint4*)Wt;
    for (int i = threadIdx.x; i < 2048; i += 256) {
        int n = i >> 4, c = i & 15;
        *(uint4*)&sW[n * 68 + c * 4] = Wt4[i];
    }
    __syncthreads();
    int l = threadIdx.x & 63;
    int w = threadIdx.x >> 6;
    int lm = l & 15;
    int q4 = l >> 4;

    floatx4 acc[2][8];
#pragma unroll
    for (int i = 0; i < 2; ++i)
#pragma unroll
        for (int j = 0; j < 8; ++j) acc[i][j] = (floatx4){0.f, 0.f, 0.f, 0.f};

    int rowbase = blockIdx.x * 128 + w * 32;
    int k8 = q4 * 8;
#pragma unroll
    for (int ks = 0; ks < 4; ++ks) {
        // A element [r][ks*32 + k8 ..] lives in quarter ks at offset k8
        short8 a[2];
#pragma unroll
        for (int mt = 0; mt < 2; ++mt) {
            int r = min(rowbase + mt * 16 + lm, N - 1);
            a[mt] = *(const short8*)(A + ((size_t)ks * N + r) * 32 + k8);
        }
#pragma unroll
        for (int nt = 0; nt < 8; ++nt) {
            short8 b = *(const short8*)&sW[(nt * 16 + lm) * 68 + ks * 16 + q4 * 4];
#pragma unroll
            for (int mt = 0; mt < 2; ++mt)
                acc[mt][nt] = __builtin_amdgcn_mfma_f32_16x16x32_bf16(b, a[mt], acc[mt][nt], 0, 0, 0);
        }
    }

    // D fragment (swapped): node = lane&15 (per mt tile), feature = nt*16 + q4*4 + reg
#pragma unroll
    for (int mt = 0; mt < 2; ++mt) {
        int gr = rowbase + mt * 16 + lm;
        if (gr < N) {
            float dv = dinv[gr];
#pragma unroll
            for (int nt = 0; nt < 8; ++nt) {
                uint2 pk;
                pk.x = pack_bf16x2(acc[mt][nt][0] * dv, acc[mt][nt][1] * dv);
                pk.y = pack_bf16x2(acc[mt][nt][2] * dv, acc[mt][nt][3] * dv);
                *(uint2*)(t + ((size_t)(nt >> 1) * N + gr) * 32 + (nt & 1) * 16 + q4 * 4) = pk;
            }
        }
    }
}

// ---------------- layer-2 aggregation: 256 nodes/block (1024 thr), 4 lanes/node -------------
// XCD-affinity swizzle: quarter = (bid%8)>>1, chunk = (bid>>3)*2 + (bid&1).
// Each XCD pair works one quarter -> 3.2 MB gather table resident in that XCD's 4 MB L2.

__global__ __launch_bounds__(1024) void agg_kernel(const unsigned short* __restrict__ t,
                                                   const int* __restrict__ row_ptr,
                                                   const int* __restrict__ bsum,
                                                   const int* __restrict__ col,
                                                   const float* __restrict__ dinv,
                                                   const float* __restrict__ bias,
                                                   unsigned short* __restrict__ out, int N, int E) {
    int nchunk = (N + 255) >> 8;
    int bid = (int)blockIdx.x;
    int r8 = bid & 7;
    int qt = r8 >> 1;                              // feature quarter 0..3 (XCD pair)
    int c = (bid >> 3) * 2 + (r8 & 1);             // node chunk
    if (c >= nchunk) return;
    int q = threadIdx.x & 3;                       // 16B col slot (8 bf16)
    int node = c * 256 + ((int)threadIdx.x >> 2);
    if (node >= N) return;
    const uint4* t4 = (const uint4*)t;
    unsigned qb = (unsigned)qt * (unsigned)N;
    int s = row_ptr[node] + bsum[node >> 10];
    int e = (node + 1 < N) ? row_ptr[node + 1] + bsum[(node + 1) >> 10] : E;
    int deg = e - s;

    float a[8];
    {   // self term
        uint4 v = t4[(size_t)((qb + (unsigned)node) * 4u + q)];
        a[0] = bf16lo(v.x); a[1] = bf16hi(v.x);
        a[2] = bf16lo(v.y); a[3] = bf16hi(v.y);
        a[4] = bf16lo(v.z); a[5] = bf16hi(v.z);
        a[6] = bf16lo(v.w); a[7] = bf16hi(v.w);
    }
    int j = 0;
    for (; j + 4 <= deg; j += 4) {
        int u0 = col[s + j];
        int u1 = col[s + j + 1];
        int u2 = col[s + j + 2];
        int u3 = col[s + j + 3];
        uint4 v0 = t4[(size_t)((qb + (unsigned)u0) * 4u + q)];
        uint4 v1 = t4[(size_t)((qb + (unsigned)u1) * 4u + q)];
        uint4 v2 = t4[(size_t)((qb + (unsigned)u2) * 4u + q)];
        uint4 v3 = t4[(size_t)((qb + (unsigned)u3) * 4u + q)];
        a[0] += bf16lo(v0.x); a[1] += bf16hi(v0.x);
        a[2] += bf16lo(v0.y); a[3] += bf16hi(v0.y);
        a[4] += bf16lo(v0.z); a[5] += bf16hi(v0.z);
        a[6] += bf16lo(v0.w); a[7] += bf16hi(v0.w);
        a[0] += bf16lo(v1.x); a[1] += bf16hi(v1.x);
        a[2] += bf16lo(v1.y); a[3] += bf16hi(v1.y);
        a[4] += bf16lo(v1.z); a[5] += bf16hi(v1.z);
        a[6] += bf16lo(v1.w); a[7] += bf16hi(v1.w);
        a[0] += bf16lo(v2.x); a[1] += bf16hi(v2.x);
        a[2] += bf16lo(v2.y); a[3] += bf16hi(v2.y);
        a[4] += bf16lo(v2.z); a[5] += bf16hi(v2.z);
        a[6] += bf16lo(v2.w); a[7] += bf16hi(v2.w);
        a[0] += bf16lo(v3.x); a[1] += bf16hi(v3.x);
        a[2] += bf16lo(v3.y); a[3] += bf16hi(v3.y);
        a[4] += bf16lo(v3.z); a[5] += bf16hi(v3.z);
        a[6] += bf16lo(v3.w); a[7] += bf16hi(v3.w);
    }
    for (; j < deg; ++j) {
        int u = col[s + j];
        uint4 v = t4[(size_t)((qb + (unsigned)u) * 4u + q)];
        a[0] += bf16lo(v.x); a[1] += bf16hi(v.x);
        a[2] += bf16lo(v.y); a[3] += bf16hi(v.y);
        a[4] += bf16lo(v.z); a[5] += bf16hi(v.z);
        a[6] += bf16lo(v.w); a[7] += bf16hi(v.w);
    }

    float dv = dinv[node];
    const float4* b4 = (const float4*)bias;
    float4 b0 = b4[qt * 8 + q * 2];
    float4 b1 = b4[qt * 8 + q * 2 + 1];
    uint4 pk;
    pk.x = pack_bf16x2(tanhf(fmaf(dv, a[0], b0.x)), tanhf(fmaf(dv, a[1], b0.y)));
    pk.y = pack_bf16x2(tanhf(fmaf(dv, a[2], b0.z)), tanhf(fmaf(dv, a[3], b0.w)));
    pk.z = pack_bf16x2(tanhf(fmaf(dv, a[4], b1.x)), tanhf(fmaf(dv, a[5], b1.y)));
    pk.w = pack_bf16x2(tanhf(fmaf(dv, a[6], b1.z)), tanhf(fmaf(dv, a[7], b1.w)));
    ((uint4*)out)[(size_t)((qb + (unsigned)node) * 4u + q)] = pk;
}

// ---------------- layer-3 aggregation + FUSED pooling (h3 never materialized) ----------------
// Same XCD-affinity swizzle. Per node: fp32 tanh outputs in-register; wave-butterfly max/sum
// when the wave's 16 nodes share a graph, merge via LDS, 128 atomics/block.

__global__ __launch_bounds__(1024) void agg3_pool(const unsigned short* __restrict__ t,
                                                  const int* __restrict__ row_ptr,
                                                  const int* __restrict__ bsum,
                                                  const int* __restrict__ col,
                                                  const float* __restrict__ dinv,
                                                  const float* __restrict__ bias,
                                                  const int* __restrict__ batch,
                                                  unsigned* __restrict__ pmax,
                                                  float* __restrict__ psum, int N, int E) {
    int nchunk = (N + 255) >> 8;
    int bid = (int)blockIdx.x;
    int r8 = bid & 7;
    int qt = r8 >> 1;
    int c = (bid >> 3) * 2 + (r8 & 1);
    if (c >= nchunk) return;

    __shared__ unsigned smax[2][32];
    __shared__ float ssum[2][32];
    if (threadIdx.x < 64) {
        smax[threadIdx.x >> 5][threadIdx.x & 31] = 0u;
        ssum[threadIdx.x >> 5][threadIdx.x & 31] = 0.f;
    }
    __syncthreads();

    int q = threadIdx.x & 3;
    int blockBase = c * 256;
    int node = blockBase + ((int)threadIdx.x >> 2);
    bool valid = node < N;
    int nc = valid ? node : N - 1;
    const uint4* t4 = (const uint4*)t;
    unsigned qb = (unsigned)qt * (unsigned)N;
    int s = row_ptr[nc] + bsum[nc >> 10];
    int e = (nc + 1 < N) ? row_ptr[nc + 1] + bsum[(nc + 1) >> 10] : E;
    int deg = valid ? (e - s) : 0;

    float a[8];
    {   // self term (of nc; discarded for invalid lanes)
        uint4 v = t4[(size_t)((qb + (unsigned)nc) * 4u + q)];
        a[0] = bf16lo(v.x); a[1] = bf16hi(v.x);
        a[2] = bf16lo(v.y); a[3] = bf16hi(v.y);
        a[4] = bf16lo(v.z); a[5] = bf16hi(v.z);
        a[6] = bf16lo(v.w); a[7] = bf16hi(v.w);
    }
    int j = 0;
    for (; j + 4 <= deg; j += 4) {
        int u0 = col[s + j];
        int u1 = col[s + j + 1];
        int u2 = col[s + j + 2];
        int u3 = col[s + j + 3];
        uint4 v0 = t4[(size_t)((qb + (unsigned)u0) * 4u + q)];
        uint4 v1 = t4[(size_t)((qb + (unsigned)u1) * 4u + q)];
        uint4 v2 = t4[(size_t)((qb + (unsigned)u2) * 4u + q)];
        uint4 v3 = t4[(size_t)((qb + (unsigned)u3) * 4u + q)];
        a[0] += bf16lo(v0.x); a[1] += bf16hi(v0.x);
        a[2] += bf16lo(v0.y); a[3] += bf16hi(v0.y);
        a[4] += bf16lo(v0.z); a[5] += bf16hi(v0.z);
        a[6] += bf16lo(v0.w); a[7] += bf16hi(v0.w);
        a[0] += bf16lo(v1.x); a[1] += bf16hi(v1.x);
        a[2] += bf16lo(v1.y); a[3] += bf16hi(v1.y);
        a[4] += bf16lo(v1.z); a[5] += bf16hi(v1.z);
        a[6] += bf16lo(v1.w); a[7] += bf16hi(v1.w);
        a[0] += bf16lo(v2.x); a[1] += bf16hi(v2.x);
        a[2] += bf16lo(v2.y); a[3] += bf16hi(v2.y);
        a[4] += bf16lo(v2.z); a[5] += bf16hi(v2.z);
        a[6] += bf16lo(v2.w); a[7] += bf16hi(v2.w);
        a[0] += bf16lo(v3.x); a[1] += bf16hi(v3.x);
        a[2] += bf16lo(v3.y); a[3] += bf16hi(v3.y);
        a[4] += bf16lo(v3.z); a[5] += bf16hi(v3.z);
        a[6] += bf16lo(v3.w); a[7] += bf16hi(v3.w);
    }
    for (; j < deg; ++j) {
        int u = col[s + j];
        uint4 v = t4[(size_t)((qb + (unsigned)u) * 4u + q)];
        a[0] += bf16lo(v.x); a[1] += bf16hi(v.x);
        a[2] += bf16lo(v.y); a[3] += bf16hi(v.y);
        a[4] += bf16lo(v.z); a[5] += bf16hi(v.z);
        a[6] += bf16lo(v.w); a[7] += bf16hi(v.w);
    }

    float dv = dinv[nc];
    const float4* b4 = (const float4*)bias;
    float4 b0 = b4[qt * 8 + q * 2];
    float4 b1 = b4[qt * 8 + q * 2 + 1];
    float o[8];
    o[0] = tanhf(fmaf(dv, a[0], b0.x)); o[1] = tanhf(fmaf(dv, a[1], b0.y));
    o[2] = tanhf(fmaf(dv, a[2], b0.z)); o[3] = tanhf(fmaf(dv, a[3], b0.w));
    o[4] = tanhf(fmaf(dv, a[4], b1.x)); o[5] = tanhf(fmaf(dv, a[5], b1.y));
    o[6] = tanhf(fmaf(dv, a[6], b1.z)); o[7] = tanhf(fmaf(dv, a[7], b1.w));

    int g = batch[nc];
    int g0 = batch[min(blockBase, N - 1)];
    int gl = __shfl(g, 0, 64);
    int gh = __shfl(g, 63, 64);

    if (gl == gh) {
        // fast path: whole wave in one graph -> butterfly reduce over the 16 node groups
        float m[8], sv[8];
#pragma unroll
        for (int k = 0; k < 8; ++k) {
            m[k] = valid ? o[k] : -3.402823466e+38f;
            sv[k] = valid ? o[k] : 0.f;
        }
#pragma unroll
        for (int st = 4; st < 64; st <<= 1) {
#pragma unroll
            for (int k = 0; k < 8; ++k) {
                m[k] = fmaxf(m[k], __shfl_xor(m[k], st, 64));
                sv[k] += __shfl_xor(sv[k], st, 64);
            }
        }
        if (((threadIdx.x & 63) >> 2) == 0) {   // 4 lanes (q=0..3) hold reduced values
            int seg = gl - g0;
            if (seg < 2) {
#pragma unroll
                for (int k = 0; k < 8; ++k) {
                    atomicMax(&smax[seg][q * 8 + k], fkey(m[k]));
                    atomicAdd(&ssum[seg][q * 8 + k], sv[k]);
                }
            } else {                            // safety net (tiny graphs)
#pragma unroll
                for (int k = 0; k < 8; ++k) {
                    atomicMax(&pmax[gl * 128 + qt * 32 + q * 8 + k], fkey(m[k]));
                    atomicAdd(&psum[gl * 128 + qt * 32 + q * 8 + k], sv[k]);
                }
            }
        }
    } else {
        // boundary wave: per-lane merge
        if (valid) {
            int seg = g - g0;
            if (seg < 2) {
#pragma unroll
                for (int k = 0; k < 8; ++k) {
                    atomicMax(&smax[seg][q * 8 + k], fkey(o[k]));
                    atomicAdd(&ssum[seg][q * 8 + k], o[k]);
                }
            } else {
#pragma unroll
                for (int k = 0; k < 8; ++k) {
                    atomicMax(&pmax[g * 128 + qt * 32 + q * 8 + k], fkey(o[k]));
                    atomicAdd(&psum[g * 128 + qt * 32 + q * 8 + k], o[k]);
                }
            }
        }
    }
    __syncthreads();
    if (threadIdx.x < 64) {
        int seg = threadIdx.x >> 5, cc = threadIdx.x & 31;
        int g0b = batch[min(blockBase, N - 1)];
        int gg = g0b + seg;
        if (gg < NGRAPH) {
            atomicMax(&pmax[gg * 128 + qt * 32 + cc], smax[seg][cc]);
            atomicAdd(&psum[gg * 128 + qt * 32 + cc], ssum[seg][cc]);
        }
    }
}

// ---------------- final: decode pooled accumulators + output head ----------------

__global__ __launch_bounds__(128) void pool_final(const unsigned* __restrict__ pmax,
                                                  const float* __restrict__ psum,
                                                  const int* __restrict__ goff,
                                                  const float* __restrict__ Wo,
                                                  const float* __restrict__ bo,
                                                  float* __restrict__ out) {
    __shared__ float p[256];
    int g = blockIdx.x;
    int j = threadIdx.x;
    int cnt = goff[g + 1] - goff[g];
    unsigned key = pmax[g * 128 + j];
    float mx = (key & 0x80000000u) ? __uint_as_float(key ^ 0x80000000u)
                                   : __uint_as_float(~key);
    p[j] = (cnt > 0) ? mx : 0.f;
    p[128 + j] = psum[g * 128 + j] / fmaxf((float)cnt, 1.f);
    __syncthreads();
    if (j < 41) {
        float acc = bo[j];
        for (int k = 0; k < 256; ++k) acc = fmaf(p[k], Wo[k * 41 + j], acc);
        out[g * 41 + j] = tanhf(acc);
    }
}

// ---------------- launch ----------------

extern "C" void kernel_launch(void* const* d_in, const int* in_sizes, int n_in,
                              void* d_out, int out_size, void* d_ws, size_t ws_size,
                              hipStream_t stream) {
    const float* x   = (const float*)d_in[0];
    const int*   ei  = (const int*)d_in[1];
    const int* batch = (const int*)d_in[2];
    const float* W1  = (const float*)d_in[3];
    const float* b1  = (const float*)d_in[4];
    const float* W2  = (const float*)d_in[5];
    const float* b2  = (const float*)d_in[6];
    const float* W3  = (const float*)d_in[7];
    const float* b3  = (const float*)d_in[8];
    const float* Wo  = (const float*)d_in[9];
    const float* bo  = (const float*)d_in[10];
    float* outp = (float*)d_out;

    int N = in_sizes[2];
    int E = in_sizes[1] / 2;
    const int* src = ei;
    const int* dst = ei + E;

    char* p = (char*)d_ws;
    auto alloc = [&](size_t bytes) -> char* {
        char* q = p;
        p += (bytes + 255) & ~(size_t)255;
        return q;
    };
    unsigned short* t   = (unsigned short*)alloc((size_t)N * 128 * 2);  // bf16 gemm out [4][N][32]
    unsigned short* hb  = (unsigned short*)alloc((size_t)N * 128 * 2);  // bf16 h1 / h2  [4][N][32]
    float* dinv   = (float*)alloc((size_t)N * 4);
    int*   rowp   = (int*)alloc((size_t)(N + 1) * 4);
    int*   col    = (int*)alloc((size_t)E * 4);
    int*   goff   = (int*)alloc(65 * 4);
    float2* y     = (float2*)alloc((size_t)N * 8);
    unsigned* Wt2 = (unsigned*)alloc(128 * 64 * 4);
    unsigned* Wt3 = (unsigned*)alloc(128 * 64 * 4);
    int nscan = (N + SCAN_BLK - 1) / SCAN_BLK;
    int*   bsum   = (int*)alloc((size_t)nscan * 4);
    // zero-init region: cnt | ticket | pmax | psum (single memset)
    size_t cntB = ((size_t)N * 4 + 255) & ~(size_t)255;
    char* zbase = alloc(cntB + 256 + NGRAPH * 128 * 4 * 2);
    int*      cnt  = (int*)zbase;
    int*      tick = (int*)(zbase + cntB);
    unsigned* pmax = (unsigned*)(zbase + cntB + 256);
    float*    psum = (float*)(zbase + cntB + 256 + NGRAPH * 128 * 4);

    (void)hipMemsetAsync(zbase, 0, cntB + 256 + NGRAPH * 128 * 4 * 2, stream);

    pack_count<<<32 + (E + 255) / 256, 256, 0, stream>>>(dst, E, cnt, W2, W3, Wt2, Wt3);
    scanA<<<nscan, SCAN_BLK, 0, stream>>>(cnt, x, rowp, bsum, dinv, y, batch, tick, goff, N);
    fill_kernel<<<(E + 255) / 256, 256, 0, stream>>>(src, dst, E, rowp, bsum, cnt, col);

    // agg grid: XCD-affinity swizzled flat grid (see agg_kernel)
    int nchunk = (N + 255) >> 8;
    int nchunkR = (nchunk + 1) & ~1;         // round up to even
    int nblk = nchunkR * 4;                  // = (nchunkR/2) * 8, multiple of 8

    // layer 1: fused agg(x) + transform -> h1 (bf16, quarter-major)
    agg_x_t1<<<(N + 255) / 256, 256, 0, stream>>>(y, rowp, bsum, col, dinv, W1, b1, hb, N, E);
    // layer 2
    gemm_mfma<<<(N + 127) / 128, 256, 0, stream>>>(hb, Wt2, dinv, t, N);
    agg_kernel<<<nblk, 1024, 0, stream>>>(t, rowp, bsum, col, dinv, b2, hb, N, E);
    // layer 3 (pooling fused into agg)
    gemm_mfma<<<(N + 127) / 128, 256, 0, stream>>>(hb, Wt3, dinv, t, N);
    agg3_pool<<<nblk, 1024, 0, stream>>>(t, rowp, bsum, col, dinv, b3, batch, pmax, psum, N, E);

    pool_final<<<NGRAPH, 128, 0, stream>>>(pmax, psum, goff, Wo, bo, outp);
}

// Round 9
// 255.901 us; speedup vs baseline: 1.1511x; 1.0211x over previous
//
#include <hip/hip_runtime.h>
#include <math.h>

#define NGRAPH 64
#define SCAN_BLK 1024
#define COLCAP 6144

typedef short short8 __attribute__((ext_vector_type(8)));
typedef float floatx4 __attribute__((ext_vector_type(4)));

__device__ inline unsigned pack_bf16x2(float a, float b) {
    unsigned ua = __float_as_uint(a);
    unsigned ub = __float_as_uint(b);
    ua = (ua + 0x7fffu + ((ua >> 16) & 1u)) >> 16;   // RNE
    ub = (ub + 0x7fffu + ((ub >> 16) & 1u)) >> 16;
    return ua | (ub << 16);
}
__device__ inline unsigned short bf16_1(float a) {
    unsigned ua = __float_as_uint(a);
    return (unsigned short)((ua + 0x7fffu + ((ua >> 16) & 1u)) >> 16);
}
__device__ inline float bf16lo(unsigned u) { return __uint_as_float(u << 16); }
__device__ inline float bf16hi(unsigned u) { return __uint_as_float(u & 0xffff0000u); }

// order-preserving float->uint key (monotone); uint 0 is below every real key -> memset-0 identity
__device__ inline unsigned fkey(float v) {
    unsigned u = __float_as_uint(v);
    return (v >= 0.f) ? (u | 0x80000000u) : ~u;
}

// All 128-wide bf16 intermediates use QUARTER-MAJOR layout: [4][N][32] bf16.
// Quarter q of node n lives at ((size_t)q * N + n) * 32 .. +31 (3.2 MB slice).
// Agg kernels: XCD-affinity swizzle (quarter = (bid%8)>>1 -> 3.2MB table resident per XCD L2),
// block-local col[] slice staged in LDS (kills 16-way-scattered 4B VMEM in the hot loop),
// branch-free masked 4-wide tail (bitwise-identical arithmetic).
// NOTE (r7): nontemporal gathers REGRESSED — nt evicts from L2 too. Plain loads.

// gather accumulate macros (expect: t4, qb, q, a[8], u0..u3 in scope)
#define TIDX(u) ((size_t)((qb + (unsigned)(u)) * 4u + (unsigned)q))
#define ACC4() do {                                                       \
    uint4 v0 = t4[TIDX(u0)]; uint4 v1 = t4[TIDX(u1)];                     \
    uint4 v2 = t4[TIDX(u2)]; uint4 v3 = t4[TIDX(u3)];                     \
    a[0] += bf16lo(v0.x); a[1] += bf16hi(v0.x);                           \
    a[2] += bf16lo(v0.y); a[3] += bf16hi(v0.y);                           \
    a[4] += bf16lo(v0.z); a[5] += bf16hi(v0.z);                           \
    a[6] += bf16lo(v0.w); a[7] += bf16hi(v0.w);                           \
    a[0] += bf16lo(v1.x); a[1] += bf16hi(v1.x);                           \
    a[2] += bf16lo(v1.y); a[3] += bf16hi(v1.y);                           \
    a[4] += bf16lo(v1.z); a[5] += bf16hi(v1.z);                           \
    a[6] += bf16lo(v1.w); a[7] += bf16hi(v1.w);                           \
    a[0] += bf16lo(v2.x); a[1] += bf16hi(v2.x);                           \
    a[2] += bf16lo(v2.y); a[3] += bf16hi(v2.y);                           \
    a[4] += bf16lo(v2.z); a[5] += bf16hi(v2.z);                           \
    a[6] += bf16lo(v2.w); a[7] += bf16hi(v2.w);                           \
    a[0] += bf16lo(v3.x); a[1] += bf16hi(v3.x);                           \
    a[2] += bf16lo(v3.y); a[3] += bf16hi(v3.y);                           \
    a[4] += bf16lo(v3.z); a[5] += bf16hi(v3.z);                           \
    a[6] += bf16lo(v3.w); a[7] += bf16hi(v3.w);                           \
} while (0)
// masked step: slot0 always valid, slots 1..3 weighted by m1..m3 in {0,1}
#define ACC4M() do {                                                      \
    uint4 v0 = t4[TIDX(u0)]; uint4 v1 = t4[TIDX(u1)];                     \
    uint4 v2 = t4[TIDX(u2)]; uint4 v3 = t4[TIDX(u3)];                     \
    a[0] += bf16lo(v0.x); a[1] += bf16hi(v0.x);                           \
    a[2] += bf16lo(v0.y); a[3] += bf16hi(v0.y);                           \
    a[4] += bf16lo(v0.z); a[5] += bf16hi(v0.z);                           \
    a[6] += bf16lo(v0.w); a[7] += bf16hi(v0.w);                           \
    a[0] = fmaf(m1, bf16lo(v1.x), a[0]); a[1] = fmaf(m1, bf16hi(v1.x), a[1]); \
    a[2] = fmaf(m1, bf16lo(v1.y), a[2]); a[3] = fmaf(m1, bf16hi(v1.y), a[3]); \
    a[4] = fmaf(m1, bf16lo(v1.z), a[4]); a[5] = fmaf(m1, bf16hi(v1.z), a[5]); \
    a[6] = fmaf(m1, bf16lo(v1.w), a[6]); a[7] = fmaf(m1, bf16hi(v1.w), a[7]); \
    a[0] = fmaf(m2, bf16lo(v2.x), a[0]); a[1] = fmaf(m2, bf16hi(v2.x), a[1]); \
    a[2] = fmaf(m2, bf16lo(v2.y), a[2]); a[3] = fmaf(m2, bf16hi(v2.y), a[3]); \
    a[4] = fmaf(m2, bf16lo(v2.z), a[4]); a[5] = fmaf(m2, bf16hi(v2.z), a[5]); \
    a[6] = fmaf(m2, bf16lo(v2.w), a[6]); a[7] = fmaf(m2, bf16hi(v2.w), a[7]); \
    a[0] = fmaf(m3, bf16lo(v3.x), a[0]); a[1] = fmaf(m3, bf16hi(v3.x), a[1]); \
    a[2] = fmaf(m3, bf16lo(v3.y), a[2]); a[3] = fmaf(m3, bf16hi(v3.y), a[3]); \
    a[4] = fmaf(m3, bf16lo(v3.z), a[4]); a[5] = fmaf(m3, bf16hi(v3.z), a[5]); \
    a[6] = fmaf(m3, bf16lo(v3.w), a[6]); a[7] = fmaf(m3, bf16hi(v3.w), a[7]); \
} while (0)

// ---------------- fused: W2/W3 transpose+bf16-pack (blocks 0..31) + degree count (rest) ----------------

__global__ void pack_count(const int* __restrict__ dst, int E, int* __restrict__ cnt,
                           const float* __restrict__ W2, const float* __restrict__ W3,
                           unsigned* __restrict__ Wt2, unsigned* __restrict__ Wt3) {
    if (blockIdx.x < 32) {
        int b = blockIdx.x;
        const float* W = (b < 16) ? W2 : W3;
        unsigned* Wt = (b < 16) ? Wt2 : Wt3;
        b &= 15;
        int bk = b & 3, bn = b >> 2;
        __shared__ float s[32][33];
        int tx = threadIdx.x & 31, ty = threadIdx.x >> 5;
#pragma unroll
        for (int r = 0; r < 4; ++r)
            s[r * 8 + ty][tx] = W[(bk * 32 + r * 8 + ty) * 128 + bn * 32 + tx];
        __syncthreads();
        int t16 = threadIdx.x & 15, tn = threadIdx.x >> 4;
#pragma unroll
        for (int pass = 0; pass < 2; ++pass) {
            int nl = pass * 16 + tn;
            unsigned pk = pack_bf16x2(s[2 * t16][nl], s[2 * t16 + 1][nl]);
            Wt[(bn * 32 + nl) * 64 + bk * 16 + t16] = pk;
        }
    } else {
        int e = (blockIdx.x - 32) * blockDim.x + threadIdx.x;
        if (e < E) atomicAdd(&cnt[dst[e]], 1);
    }
}

// ---- fused scan: per-block exclusive scan + last-block closes (block-offset scan + goff) ----
// Consumers compute final row_ptr as row_ptr[i] + bsum[i>>10] on the fly.

__global__ __launch_bounds__(SCAN_BLK) void scanA(const int* __restrict__ cnt,
                                                  const float* __restrict__ x,
                                                  int* __restrict__ row_ptr,
                                                  int* __restrict__ bsum,
                                                  float* __restrict__ dinv,
                                                  float2* __restrict__ y,
                                                  const int* __restrict__ batch,
                                                  int* __restrict__ ticket,
                                                  int* __restrict__ goff, int N) {
    __shared__ int sm[SCAN_BLK];
    __shared__ int amLast;
    int i = blockIdx.x * SCAN_BLK + threadIdx.x;
    int v = (i < N) ? cnt[i] : 0;
    if (i < N) {
        float dv = rsqrtf((float)v + 1.0f);
        dinv[i] = dv;
        float2 xv = ((const float2*)x)[i];
        y[i] = make_float2(xv.x * dv, xv.y * dv);
    }
    sm[threadIdx.x] = v;
    __syncthreads();
    for (int off = 1; off < SCAN_BLK; off <<= 1) {
        int t = (threadIdx.x >= (unsigned)off) ? sm[threadIdx.x - off] : 0;
        __syncthreads();
        sm[threadIdx.x] += t;
        __syncthreads();
    }
    if (i < N) row_ptr[i] = sm[threadIdx.x] - v;
    if (threadIdx.x == SCAN_BLK - 1) bsum[blockIdx.x] = sm[SCAN_BLK - 1];
    __syncthreads();                       // all block stores issued & drained
    if (threadIdx.x == 0) {
        __threadfence();                   // publish this block's stores device-wide
        amLast = (atomicAdd(ticket, 1) == (int)gridDim.x - 1);
    }
    __syncthreads();
    if (!amLast) return;
    // closer block: exclusive-scan the block sums (coherent atomic reads), compute goff
    int nb = (int)gridDim.x;
    int v2 = (threadIdx.x < (unsigned)nb) ? atomicAdd(&bsum[threadIdx.x], 0) : 0;
    sm[threadIdx.x] = v2;
    __syncthreads();
    for (int off = 1; off < SCAN_BLK; off <<= 1) {
        int t = (threadIdx.x >= (unsigned)off) ? sm[threadIdx.x - off] : 0;
        __syncthreads();
        sm[threadIdx.x] += t;
        __syncthreads();
    }
    if (threadIdx.x < (unsigned)nb) bsum[threadIdx.x] = sm[threadIdx.x] - v2;
    if (threadIdx.x <= NGRAPH) {
        int g = threadIdx.x;
        int lo = 0, hi = N;
        while (lo < hi) {
            int mid = (lo + hi) >> 1;
            if (batch[mid] < g) lo = mid + 1; else hi = mid;
        }
        goff[g] = lo;
    }
}

// reverse-fill using cnt itself (dead after scan); applies block offset on the fly
__global__ void fill_kernel(const int* __restrict__ src, const int* __restrict__ dst, int E,
                            const int* __restrict__ row_ptr, const int* __restrict__ bsum,
                            int* __restrict__ cnt, int* __restrict__ col) {
    int e = blockIdx.x * blockDim.x + threadIdx.x;
    if (e < E) {
        int d = dst[e];
        int base = row_ptr[d] + bsum[d >> 10];
        int p = base + atomicSub(&cnt[d], 1) - 1;
        col[p] = src[e];
    }
}

// ---------------- layer 1 fused: z = agg(y) ; h1 = tanh(z @ W1 + b1) (bf16, quarter-major out) --------

__global__ __launch_bounds__(256) void agg_x_t1(const float2* __restrict__ y,
                                                const int* __restrict__ row_ptr,
                                                const int* __restrict__ bsum,
                                                const int* __restrict__ col,
                                                const float* __restrict__ dinv,
                                                const float* __restrict__ W1,
                                                const float* __restrict__ b1,
                                                unsigned short* __restrict__ h, int N, int E) {
    __shared__ float4 sW[64];     // W1[2][128]
    __shared__ float4 sb[32];     // b1[128]
    __shared__ float2 zs[256];
    if (threadIdx.x < 64) sW[threadIdx.x] = ((const float4*)W1)[threadIdx.x];
    if (threadIdx.x < 32) sb[threadIdx.x] = ((const float4*)b1)[threadIdx.x];

    int v = blockIdx.x * 256 + threadIdx.x;
    float2 zv = make_float2(0.f, 0.f);
    if (v < N) {
        int s = row_ptr[v] + bsum[v >> 10];
        int e = (v + 1 < N) ? row_ptr[v + 1] + bsum[(v + 1) >> 10] : E;
        float2 a0 = y[v];
        float2 a1 = make_float2(0.f, 0.f);
        float2 a2 = make_float2(0.f, 0.f);
        float2 a3 = make_float2(0.f, 0.f);
        int j = s;
        for (; j + 4 <= e; j += 4) {
            int u0 = col[j], u1 = col[j + 1], u2 = col[j + 2], u3 = col[j + 3];
            float2 v0 = y[u0], v1 = y[u1], v2 = y[u2], v3 = y[u3];
            a0.x += v0.x; a0.y += v0.y;
            a1.x += v1.x; a1.y += v1.y;
            a2.x += v2.x; a2.y += v2.y;
            a3.x += v3.x; a3.y += v3.y;
        }
        for (; j < e; ++j) {
            float2 vv = y[col[j]];
            a0.x += vv.x; a0.y += vv.y;
        }
        float dv = dinv[v];
        zv = make_float2(dv * (a0.x + a1.x + a2.x + a3.x),
                         dv * (a0.y + a1.y + a2.y + a3.y));
    }
    zs[threadIdx.x] = zv;
    __syncthreads();

    int q = threadIdx.x & 31;          // col quad (4 cols)
    int rsub = threadIdx.x >> 5;       // 0..7
    float4 w0 = sW[q];
    float4 w1 = sW[32 + q];
    float4 b = sb[q];
    size_t qoff = (size_t)(q >> 3) * N;  // quarter base (rows)
#pragma unroll 4
    for (int pass = 0; pass < 32; ++pass) {
        int local = pass * 8 + rsub;
        int row = blockIdx.x * 256 + local;
        if (row >= N) break;
        float2 z = zs[local];
        float ox = tanhf(fmaf(z.x, w0.x, fmaf(z.y, w1.x, b.x)));
        float oy = tanhf(fmaf(z.x, w0.y, fmaf(z.y, w1.y, b.y)));
        float oz = tanhf(fmaf(z.x, w0.z, fmaf(z.y, w1.z, b.z)));
        float ow = tanhf(fmaf(z.x, w0.w, fmaf(z.y, w1.w, b.w)));
        uint2 pk;
        pk.x = pack_bf16x2(ox, oy);
        pk.y = pack_bf16x2(oz, ow);
        ((uint2*)h)[(qoff + row) * 8 + (q & 7)] = pk;
    }
}

// ---------------- MFMA GEMM: t[4][N][32](bf16) = (A[4][N][32](bf16) @ W) * dinv ----------------
// Operands SWAPPED vs naive: mfma(W_frag, A_frag, acc) computes the transposed fragment, so
// lane&15 indexes the NODE and reg 0..3 indexes 4 consecutive features -> 8B uint2 stores.

__global__ __launch_bounds__(256) void gemm_mfma(const unsigned short* __restrict__ A,
                                                 const unsigned* __restrict__ Wt,
                                                 const float* __restrict__ dinv,
                                                 unsigned short* __restrict__ t, int N) {
    __shared__ unsigned sW[128 * 68];
    const uint4* Wt4 = (const uint4*)Wt;
    for (int i = threadIdx.x; i < 2048; i += 256) {
        int n = i >> 4, c = i & 15;
        *(uint4*)&sW[n * 68 + c * 4] = Wt4[i];
    }
    __syncthreads();
    int l = threadIdx.x & 63;
    int w = threadIdx.x >> 6;
    int lm = l & 15;
    int q4 = l >> 4;

    floatx4 acc[2][8];
#pragma unroll
    for (int i = 0; i < 2; ++i)
#pragma unroll
        for (int j = 0; j < 8; ++j) acc[i][j] = (floatx4){0.f, 0.f, 0.f, 0.f};

    int rowbase = blockIdx.x * 128 + w * 32;
    int k8 = q4 * 8;
#pragma unroll
    for (int ks = 0; ks < 4; ++ks) {
        // A element [r][ks*32 + k8 ..] lives in quarter ks at offset k8
        short8 a[2];
#pragma unroll
        for (int mt = 0; mt < 2; ++mt) {
            int r = min(rowbase + mt * 16 + lm, N - 1);
            a[mt] = *(const short8*)(A + ((size_t)ks * N + r) * 32 + k8);
        }
#pragma unroll
        for (int nt = 0; nt < 8; ++nt) {
            short8 b = *(const short8*)&sW[(nt * 16 + lm) * 68 + ks * 16 + q4 * 4];
#pragma unroll
            for (int mt = 0; mt < 2; ++mt)
                acc[mt][nt] = __builtin_amdgcn_mfma_f32_16x16x32_bf16(b, a[mt], acc[mt][nt], 0, 0, 0);
        }
    }

    // D fragment (swapped): node = lane&15 (per mt tile), feature = nt*16 + q4*4 + reg
#pragma unroll
    for (int mt = 0; mt < 2; ++mt) {
        int gr = rowbase + mt * 16 + lm;
        if (gr < N) {
            float dv = dinv[gr];
#pragma unroll
            for (int nt = 0; nt < 8; ++nt) {
                uint2 pk;
                pk.x = pack_bf16x2(acc[mt][nt][0] * dv, acc[mt][nt][1] * dv);
                pk.y = pack_bf16x2(acc[mt][nt][2] * dv, acc[mt][nt][3] * dv);
                *(uint2*)(t + ((size_t)(nt >> 1) * N + gr) * 32 + (nt & 1) * 16 + q4 * 4) = pk;
            }
        }
    }
}

// ---------------- layer-2 aggregation: 256 nodes/block (1024 thr), 4 lanes/node -------------
// XCD-affinity swizzle + LDS-staged col slice + masked 4-wide tail.

__global__ __launch_bounds__(1024) void agg_kernel(const unsigned short* __restrict__ t,
                                                   const int* __restrict__ row_ptr,
                                                   const int* __restrict__ bsum,
                                                   const int* __restrict__ col,
                                                   const float* __restrict__ dinv,
                                                   const float* __restrict__ bias,
                                                   unsigned short* __restrict__ out, int N, int E) {
    int nchunk = (N + 255) >> 8;
    int bid = (int)blockIdx.x;
    int r8 = bid & 7;
    int qt = r8 >> 1;                              // feature quarter 0..3 (XCD pair)
    int c = (bid >> 3) * 2 + (r8 & 1);             // node chunk
    if (c >= nchunk) return;

    __shared__ int scol[COLCAP];
    int firstNode = c * 256;
    int lastNode = min(firstNode + 256, N);
    int sBase = row_ptr[firstNode] + bsum[firstNode >> 10];
    int eEnd = (lastNode < N) ? row_ptr[lastNode] + bsum[lastNode >> 10] : E;
    int range = eEnd - sBase;
    bool inLds = (range <= COLCAP);
    if (inLds) {
        for (int i = threadIdx.x; i < range; i += 1024) scol[i] = col[sBase + i];
    }
    __syncthreads();

    int q = threadIdx.x & 3;                       // 16B col slot (8 bf16)
    int node = firstNode + ((int)threadIdx.x >> 2);
    if (node >= N) return;
    const uint4* t4 = (const uint4*)t;
    unsigned qb = (unsigned)qt * (unsigned)N;
    int s = row_ptr[node] + bsum[node >> 10];
    int e = (node + 1 < N) ? row_ptr[node + 1] + bsum[(node + 1) >> 10] : E;
    int deg = e - s;

    float a[8];
    {   // self term
        uint4 v = t4[TIDX(node)];
        a[0] = bf16lo(v.x); a[1] = bf16hi(v.x);
        a[2] = bf16lo(v.y); a[3] = bf16hi(v.y);
        a[4] = bf16lo(v.z); a[5] = bf16hi(v.z);
        a[6] = bf16lo(v.w); a[7] = bf16hi(v.w);
    }
    int j = 0;
    if (inLds) {
        int sl = s - sBase;
        for (; j + 4 <= deg; j += 4) {
            int u0 = scol[sl + j], u1 = scol[sl + j + 1];
            int u2 = scol[sl + j + 2], u3 = scol[sl + j + 3];
            ACC4();
        }
        if (j < deg) {
            float m1 = (j + 1 < deg) ? 1.f : 0.f;
            float m2 = (j + 2 < deg) ? 1.f : 0.f;
            float m3 = (j + 3 < deg) ? 1.f : 0.f;
            int u0 = scol[sl + j];
            int u1 = scol[sl + min(j + 1, deg - 1)];
            int u2 = scol[sl + min(j + 2, deg - 1)];
            int u3 = scol[sl + min(j + 3, deg - 1)];
            ACC4M();
        }
    } else {
        for (; j + 4 <= deg; j += 4) {
            int u0 = col[s + j], u1 = col[s + j + 1];
            int u2 = col[s + j + 2], u3 = col[s + j + 3];
            ACC4();
        }
        if (j < deg) {
            float m1 = (j + 1 < deg) ? 1.f : 0.f;
            float m2 = (j + 2 < deg) ? 1.f : 0.f;
            float m3 = (j + 3 < deg) ? 1.f : 0.f;
            int u0 = col[s + j];
            int u1 = col[s + min(j + 1, deg - 1)];
            int u2 = col[s + min(j + 2, deg - 1)];
            int u3 = col[s + min(j + 3, deg - 1)];
            ACC4M();
        }
    }

    float dv = dinv[node];
    const float4* b4 = (const float4*)bias;
    float4 b0 = b4[qt * 8 + q * 2];
    float4 b1 = b4[qt * 8 + q * 2 + 1];
    uint4 pk;
    pk.x = pack_bf16x2(tanhf(fmaf(dv, a[0], b0.x)), tanhf(fmaf(dv, a[1], b0.y)));
    pk.y = pack_bf16x2(tanhf(fmaf(dv, a[2], b0.z)), tanhf(fmaf(dv, a[3], b0.w)));
    pk.z = pack_bf16x2(tanhf(fmaf(dv, a[4], b1.x)), tanhf(fmaf(dv, a[5], b1.y)));
    pk.w = pack_bf16x2(tanhf(fmaf(dv, a[6], b1.z)), tanhf(fmaf(dv, a[7], b1.w)));
    ((uint4*)out)[TIDX(node)] = pk;
}

// ---------------- layer-3 aggregation + FUSED pooling (h3 never materialized) ----------------
// Same structure; fp32 tanh in-register; wave-butterfly max/sum, LDS merge, 128 atomics/block.

__global__ __launch_bounds__(1024) void agg3_pool(const unsigned short* __restrict__ t,
                                                  const int* __restrict__ row_ptr,
                                                  const int* __restrict__ bsum,
                                                  const int* __restrict__ col,
                                                  const float* __restrict__ dinv,
                                                  const float* __restrict__ bias,
                                                  const int* __restrict__ batch,
                                                  unsigned* __restrict__ pmax,
                                                  float* __restrict__ psum, int N, int E) {
    int nchunk = (N + 255) >> 8;
    int bid = (int)blockIdx.x;
    int r8 = bid & 7;
    int qt = r8 >> 1;
    int c = (bid >> 3) * 2 + (r8 & 1);
    if (c >= nchunk) return;

    __shared__ unsigned smax[2][32];
    __shared__ float ssum[2][32];
    __shared__ int scol[COLCAP];
    if (threadIdx.x < 64) {
        smax[threadIdx.x >> 5][threadIdx.x & 31] = 0u;
        ssum[threadIdx.x >> 5][threadIdx.x & 31] = 0.f;
    }
    int firstNode = c * 256;
    int lastNode = min(firstNode + 256, N);
    int sBase = row_ptr[firstNode] + bsum[firstNode >> 10];
    int eEnd = (lastNode < N) ? row_ptr[lastNode] + bsum[lastNode >> 10] : E;
    int range = eEnd - sBase;
    bool inLds = (range <= COLCAP);
    if (inLds) {
        for (int i = threadIdx.x; i < range; i += 1024) scol[i] = col[sBase + i];
    }
    __syncthreads();

    int q = threadIdx.x & 3;
    int blockBase = firstNode;
    int node = blockBase + ((int)threadIdx.x >> 2);
    bool valid = node < N;
    int nc = valid ? node : N - 1;
    const uint4* t4 = (const uint4*)t;
    unsigned qb = (unsigned)qt * (unsigned)N;
    int s = row_ptr[nc] + bsum[nc >> 10];
    int e = (nc + 1 < N) ? row_ptr[nc + 1] + bsum[(nc + 1) >> 10] : E;
    int deg = valid ? (e - s) : 0;

    float a[8];
    {   // self term (of nc; discarded for invalid lanes)
        uint4 v = t4[TIDX(nc)];
        a[0] = bf16lo(v.x); a[1] = bf16hi(v.x);
        a[2] = bf16lo(v.y); a[3] = bf16hi(v.y);
        a[4] = bf16lo(v.z); a[5] = bf16hi(v.z);
        a[6] = bf16lo(v.w); a[7] = bf16hi(v.w);
    }
    int j = 0;
    if (inLds) {
        int sl = s - sBase;
        for (; j + 4 <= deg; j += 4) {
            int u0 = scol[sl + j], u1 = scol[sl + j + 1];
            int u2 = scol[sl + j + 2], u3 = scol[sl + j + 3];
            ACC4();
        }
        if (j < deg) {
            float m1 = (j + 1 < deg) ? 1.f : 0.f;
            float m2 = (j + 2 < deg) ? 1.f : 0.f;
            float m3 = (j + 3 < deg) ? 1.f : 0.f;
            int u0 = scol[sl + j];
            int u1 = scol[sl + min(j + 1, deg - 1)];
            int u2 = scol[sl + min(j + 2, deg - 1)];
            int u3 = scol[sl + min(j + 3, deg - 1)];
            ACC4M();
        }
    } else {
        for (; j + 4 <= deg; j += 4) {
            int u0 = col[s + j], u1 = col[s + j + 1];
            int u2 = col[s + j + 2], u3 = col[s + j + 3];
            ACC4();
        }
        if (j < deg) {
            float m1 = (j + 1 < deg) ? 1.f : 0.f;
            float m2 = (j + 2 < deg) ? 1.f : 0.f;
            float m3 = (j + 3 < deg) ? 1.f : 0.f;
            int u0 = col[s + j];
            int u1 = col[s + min(j + 1, deg - 1)];
            int u2 = col[s + min(j + 2, deg - 1)];
            int u3 = col[s + min(j + 3, deg - 1)];
            ACC4M();
        }
    }

    float dv = dinv[nc];
    const float4* b4 = (const float4*)bias;
    float4 b0 = b4[qt * 8 + q * 2];
    float4 b1 = b4[qt * 8 + q * 2 + 1];
    float o[8];
    o[0] = tanhf(fmaf(dv, a[0], b0.x)); o[1] = tanhf(fmaf(dv, a[1], b0.y));
    o[2] = tanhf(fmaf(dv, a[2], b0.z)); o[3] = tanhf(fmaf(dv, a[3], b0.w));
    o[4] = tanhf(fmaf(dv, a[4], b1.x)); o[5] = tanhf(fmaf(dv, a[5], b1.y));
    o[6] = tanhf(fmaf(dv, a[6], b1.z)); o[7] = tanhf(fmaf(dv, a[7], b1.w));

    int g = batch[nc];
    int g0 = batch[min(blockBase, N - 1)];
    int gl = __shfl(g, 0, 64);
    int gh = __shfl(g, 63, 64);

    if (gl == gh) {
        // fast path: whole wave in one graph -> butterfly reduce over the 16 node groups
        float m[8], sv[8];
#pragma unroll
        for (int k = 0; k < 8; ++k) {
            m[k] = valid ? o[k] : -3.402823466e+38f;
            sv[k] = valid ? o[k] : 0.f;
        }
#pragma unroll
        for (int st = 4; st < 64; st <<= 1) {
#pragma unroll
            for (int k = 0; k < 8; ++k) {
                m[k] = fmaxf(m[k], __shfl_xor(m[k], st, 64));
                sv[k] += __shfl_xor(sv[k], st, 64);
            }
        }
        if (((threadIdx.x & 63) >> 2) == 0) {   // 4 lanes (q=0..3) hold reduced values
            int seg = gl - g0;
            if (seg < 2) {
#pragma unroll
                for (int k = 0; k < 8; ++k) {
                    atomicMax(&smax[seg][q * 8 + k], fkey(m[k]));
                    atomicAdd(&ssum[seg][q * 8 + k], sv[k]);
                }
            } else {                            // safety net (tiny graphs)
#pragma unroll
                for (int k = 0; k < 8; ++k) {
                    atomicMax(&pmax[gl * 128 + qt * 32 + q * 8 + k], fkey(m[k]));
                    atomicAdd(&psum[gl * 128 + qt * 32 + q * 8 + k], sv[k]);
                }
            }
        }
    } else {
        // boundary wave: per-lane merge
        if (valid) {
            int seg = g - g0;
            if (seg < 2) {
#pragma unroll
                for (int k = 0; k < 8; ++k) {
                    atomicMax(&smax[seg][q * 8 + k], fkey(o[k]));
                    atomicAdd(&ssum[seg][q * 8 + k], o[k]);
                }
            } else {
#pragma unroll
                for (int k = 0; k < 8; ++k) {
                    atomicMax(&pmax[g * 128 + qt * 32 + q * 8 + k], fkey(o[k]));
                    atomicAdd(&psum[g * 128 + qt * 32 + q * 8 + k], o[k]);
                }
            }
        }
    }
    __syncthreads();
    if (threadIdx.x < 64) {
        int seg = threadIdx.x >> 5, cc = threadIdx.x & 31;
        int g0b = batch[min(blockBase, N - 1)];
        int gg = g0b + seg;
        if (gg < NGRAPH) {
            atomicMax(&pmax[gg * 128 + qt * 32 + cc], smax[seg][cc]);
            atomicAdd(&psum[gg * 128 + qt * 32 + cc], ssum[seg][cc]);
        }
    }
}

// ---------------- final: decode pooled accumulators + output head ----------------

__global__ __launch_bounds__(128) void pool_final(const unsigned* __restrict__ pmax,
                                                  const float* __restrict__ psum,
                                                  const int* __restrict__ goff,
                                                  const float* __restrict__ Wo,
                                                  const float* __restrict__ bo,
                                                  float* __restrict__ out) {
    __shared__ float p[256];
    int g = blockIdx.x;
    int j = threadIdx.x;
    int cnt = goff[g + 1] - goff[g];
    unsigned key = pmax[g * 128 + j];
    float mx = (key & 0x80000000u) ? __uint_as_float(key ^ 0x80000000u)
                                   : __uint_as_float(~key);
    p[j] = (cnt > 0) ? mx : 0.f;
    p[128 + j] = psum[g * 128 + j] / fmaxf((float)cnt, 1.f);
    __syncthreads();
    if (j < 41) {
        float acc = bo[j];
        for (int k = 0; k < 256; ++k) acc = fmaf(p[k], Wo[k * 41 + j], acc);
        out[g * 41 + j] = tanhf(acc);
    }
}

// ---------------- launch ----------------

extern "C" void kernel_launch(void* const* d_in, const int* in_sizes, int n_in,
                              void* d_out, int out_size, void* d_ws, size_t ws_size,
                              hipStream_t stream) {
    const float* x   = (const float*)d_in[0];
    const int*   ei  = (const int*)d_in[1];
    const int* batch = (const int*)d_in[2];
    const float* W1  = (const float*)d_in[3];
    const float* b1  = (const float*)d_in[4];
    const float* W2  = (const float*)d_in[5];
    const float* b2  = (const float*)d_in[6];
    const float* W3  = (const float*)d_in[7];
    const float* b3  = (const float*)d_in[8];
    const float* Wo  = (const float*)d_in[9];
    const float* bo  = (const float*)d_in[10];
    float* outp = (float*)d_out;

    int N = in_sizes[2];
    int E = in_sizes[1] / 2;
    const int* src = ei;
    const int* dst = ei + E;

    char* p = (char*)d_ws;
    auto alloc = [&](size_t bytes) -> char* {
        char* q = p;
        p += (bytes + 255) & ~(size_t)255;
        return q;
    };
    unsigned short* t   = (unsigned short*)alloc((size_t)N * 128 * 2);  // bf16 gemm out [4][N][32]
    unsigned short* hb  = (unsigned short*)alloc((size_t)N * 128 * 2);  // bf16 h1 / h2  [4][N][32]
    float* dinv   = (float*)alloc((size_t)N * 4);
    int*   rowp   = (int*)alloc((size_t)(N + 1) * 4);
    int*   col    = (int*)alloc((size_t)E * 4);
    int*   goff   = (int*)alloc(65 * 4);
    float2* y     = (float2*)alloc((size_t)N * 8);
    unsigned* Wt2 = (unsigned*)alloc(128 * 64 * 4);
    unsigned* Wt3 = (unsigned*)alloc(128 * 64 * 4);
    int nscan = (N + SCAN_BLK - 1) / SCAN_BLK;
    int*   bsum   = (int*)alloc((size_t)nscan * 4);
    // zero-init region: cnt | ticket | pmax | psum (single memset)
    size_t cntB = ((size_t)N * 4 + 255) & ~(size_t)255;
    char* zbase = alloc(cntB + 256 + NGRAPH * 128 * 4 * 2);
    int*      cnt  = (int*)zbase;
    int*      tick = (int*)(zbase + cntB);
    unsigned* pmax = (unsigned*)(zbase + cntB + 256);
    float*    psum = (float*)(zbase + cntB + 256 + NGRAPH * 128 * 4);

    (void)hipMemsetAsync(zbase, 0, cntB + 256 + NGRAPH * 128 * 4 * 2, stream);

    pack_count<<<32 + (E + 255) / 256, 256, 0, stream>>>(dst, E, cnt, W2, W3, Wt2, Wt3);
    scanA<<<nscan, SCAN_BLK, 0, stream>>>(cnt, x, rowp, bsum, dinv, y, batch, tick, goff, N);
    fill_kernel<<<(E + 255) / 256, 256, 0, stream>>>(src, dst, E, rowp, bsum, cnt, col);

    // agg grid: XCD-affinity swizzled flat grid (see agg_kernel)
    int nchunk = (N + 255) >> 8;
    int nchunkR = (nchunk + 1) & ~1;         // round up to even
    int nblk = nchunkR * 4;                  // = (nchunkR/2) * 8, multiple of 8

    // layer 1: fused agg(x) + transform -> h1 (bf16, quarter-major)
    agg_x_t1<<<(N + 255) / 256, 256, 0, stream>>>(y, rowp, bsum, col, dinv, W1, b1, hb, N, E);
    // layer 2
    gemm_mfma<<<(N + 127) / 128, 256, 0, stream>>>(hb, Wt2, dinv, t, N);
    agg_kernel<<<nblk, 1024, 0, stream>>>(t, rowp, bsum, col, dinv, b2, hb, N, E);
    // layer 3 (pooling fused into agg)
    gemm_mfma<<<(N + 127) / 128, 256, 0, stream>>>(hb, Wt3, dinv, t, N);
    agg3_pool<<<nblk, 1024, 0, stream>>>(t, rowp, bsum, col, dinv, b3, batch, pmax, psum, N, E);

    pool_final<<<NGRAPH, 128, 0, stream>>>(pmax, psum, goff, Wo, bo, outp);
}

// Round 10
// 228.716 us; speedup vs baseline: 1.2880x; 1.1189x over previous
//
#include <hip/hip_runtime.h>
#include <math.h>

#define NGRAPH 64
#define SCAN_BLK 1024
#define COLCAP 6144
#define AXCAP 2560

typedef short short8 __attribute__((ext_vector_type(8)));
typedef float floatx4 __attribute__((ext_vector_type(4)));

__device__ inline unsigned pack_bf16x2(float a, float b) {
    unsigned ua = __float_as_uint(a);
    unsigned ub = __float_as_uint(b);
    ua = (ua + 0x7fffu + ((ua >> 16) & 1u)) >> 16;   // RNE
    ub = (ub + 0x7fffu + ((ub >> 16) & 1u)) >> 16;
    return ua | (ub << 16);
}
__device__ inline unsigned short bf16_1(float a) {
    unsigned ua = __float_as_uint(a);
    return (unsigned short)((ua + 0x7fffu + ((ua >> 16) & 1u)) >> 16);
}
__device__ inline float bf16lo(unsigned u) { return __uint_as_float(u << 16); }
__device__ inline float bf16hi(unsigned u) { return __uint_as_float(u & 0xffff0000u); }

// order-preserving float->uint key (monotone); uint 0 is below every real key -> memset-0 identity
__device__ inline unsigned fkey(float v) {
    unsigned u = __float_as_uint(v);
    return (v >= 0.f) ? (u | 0x80000000u) : ~u;
}

// All 128-wide bf16 intermediates use QUARTER-MAJOR layout: [4][N][32] bf16.
// Agg kernels: XCD-affinity swizzle (quarter = (bid%8)>>1 -> 3.2MB table resident per XCD L2),
// block-local col[] slice staged in LDS, branch-free masked 4-wide tail.
// NOTE (r7): nontemporal gathers REGRESSED — nt evicts from L2 too. Plain loads.
// r10: agg_x_t1 4 lanes/node (latency hiding 3->12 waves/CU); fill uses rank[] (no atomic).

#define TIDX(u) ((size_t)((qb + (unsigned)(u)) * 4u + (unsigned)q))
#define ACC4() do {                                                       \
    uint4 v0 = t4[TIDX(u0)]; uint4 v1 = t4[TIDX(u1)];                     \
    uint4 v2 = t4[TIDX(u2)]; uint4 v3 = t4[TIDX(u3)];                     \
    a[0] += bf16lo(v0.x); a[1] += bf16hi(v0.x);                           \
    a[2] += bf16lo(v0.y); a[3] += bf16hi(v0.y);                           \
    a[4] += bf16lo(v0.z); a[5] += bf16hi(v0.z);                           \
    a[6] += bf16lo(v0.w); a[7] += bf16hi(v0.w);                           \
    a[0] += bf16lo(v1.x); a[1] += bf16hi(v1.x);                           \
    a[2] += bf16lo(v1.y); a[3] += bf16hi(v1.y);                           \
    a[4] += bf16lo(v1.z); a[5] += bf16hi(v1.z);                           \
    a[6] += bf16lo(v1.w); a[7] += bf16hi(v1.w);                           \
    a[0] += bf16lo(v2.x); a[1] += bf16hi(v2.x);                           \
    a[2] += bf16lo(v2.y); a[3] += bf16hi(v2.y);                           \
    a[4] += bf16lo(v2.z); a[5] += bf16hi(v2.z);                           \
    a[6] += bf16lo(v2.w); a[7] += bf16hi(v2.w);                           \
    a[0] += bf16lo(v3.x); a[1] += bf16hi(v3.x);                           \
    a[2] += bf16lo(v3.y); a[3] += bf16hi(v3.y);                           \
    a[4] += bf16lo(v3.z); a[5] += bf16hi(v3.z);                           \
    a[6] += bf16lo(v3.w); a[7] += bf16hi(v3.w);                           \
} while (0)
#define ACC4M() do {                                                      \
    uint4 v0 = t4[TIDX(u0)]; uint4 v1 = t4[TIDX(u1)];                     \
    uint4 v2 = t4[TIDX(u2)]; uint4 v3 = t4[TIDX(u3)];                     \
    a[0] += bf16lo(v0.x); a[1] += bf16hi(v0.x);                           \
    a[2] += bf16lo(v0.y); a[3] += bf16hi(v0.y);                           \
    a[4] += bf16lo(v0.z); a[5] += bf16hi(v0.z);                           \
    a[6] += bf16lo(v0.w); a[7] += bf16hi(v0.w);                           \
    a[0] = fmaf(m1, bf16lo(v1.x), a[0]); a[1] = fmaf(m1, bf16hi(v1.x), a[1]); \
    a[2] = fmaf(m1, bf16lo(v1.y), a[2]); a[3] = fmaf(m1, bf16hi(v1.y), a[3]); \
    a[4] = fmaf(m1, bf16lo(v1.z), a[4]); a[5] = fmaf(m1, bf16hi(v1.z), a[5]); \
    a[6] = fmaf(m1, bf16lo(v1.w), a[6]); a[7] = fmaf(m1, bf16hi(v1.w), a[7]); \
    a[0] = fmaf(m2, bf16lo(v2.x), a[0]); a[1] = fmaf(m2, bf16hi(v2.x), a[1]); \
    a[2] = fmaf(m2, bf16lo(v2.y), a[2]); a[3] = fmaf(m2, bf16hi(v2.y), a[3]); \
    a[4] = fmaf(m2, bf16lo(v2.z), a[4]); a[5] = fmaf(m2, bf16hi(v2.z), a[5]); \
    a[6] = fmaf(m2, bf16lo(v2.w), a[6]); a[7] = fmaf(m2, bf16hi(v2.w), a[7]); \
    a[0] = fmaf(m3, bf16lo(v3.x), a[0]); a[1] = fmaf(m3, bf16hi(v3.x), a[1]); \
    a[2] = fmaf(m3, bf16lo(v3.y), a[2]); a[3] = fmaf(m3, bf16hi(v3.y), a[3]); \
    a[4] = fmaf(m3, bf16lo(v3.z), a[4]); a[5] = fmaf(m3, bf16hi(v3.z), a[5]); \
    a[6] = fmaf(m3, bf16lo(v3.w), a[6]); a[7] = fmaf(m3, bf16hi(v3.w), a[7]); \
} while (0)

// ---------------- fused: W2/W3 transpose+bf16-pack (blocks 0..31) + degree count + rank (rest) --------

__global__ void pack_count(const int* __restrict__ dst, int E, int* __restrict__ cnt,
                           int* __restrict__ rank,
                           const float* __restrict__ W2, const float* __restrict__ W3,
                           unsigned* __restrict__ Wt2, unsigned* __restrict__ Wt3) {
    if (blockIdx.x < 32) {
        int b = blockIdx.x;
        const float* W = (b < 16) ? W2 : W3;
        unsigned* Wt = (b < 16) ? Wt2 : Wt3;
        b &= 15;
        int bk = b & 3, bn = b >> 2;
        __shared__ float s[32][33];
        int tx = threadIdx.x & 31, ty = threadIdx.x >> 5;
#pragma unroll
        for (int r = 0; r < 4; ++r)
            s[r * 8 + ty][tx] = W[(bk * 32 + r * 8 + ty) * 128 + bn * 32 + tx];
        __syncthreads();
        int t16 = threadIdx.x & 15, tn = threadIdx.x >> 4;
#pragma unroll
        for (int pass = 0; pass < 2; ++pass) {
            int nl = pass * 16 + tn;
            unsigned pk = pack_bf16x2(s[2 * t16][nl], s[2 * t16 + 1][nl]);
            Wt[(bn * 32 + nl) * 64 + bk * 16 + t16] = pk;
        }
    } else {
        int e = (blockIdx.x - 32) * blockDim.x + threadIdx.x;
        if (e < E) rank[e] = atomicAdd(&cnt[dst[e]], 1);
    }
}

// ---- fused scan: per-block exclusive scan + last-block closes (block-offset scan + goff) ----
// Consumers compute final row_ptr as row_ptr[i] + bsum[i>>10] on the fly.

__global__ __launch_bounds__(SCAN_BLK) void scanA(const int* __restrict__ cnt,
                                                  const float* __restrict__ x,
                                                  int* __restrict__ row_ptr,
                                                  int* __restrict__ bsum,
                                                  float* __restrict__ dinv,
                                                  float2* __restrict__ y,
                                                  const int* __restrict__ batch,
                                                  int* __restrict__ ticket,
                                                  int* __restrict__ goff, int N) {
    __shared__ int sm[SCAN_BLK];
    __shared__ int amLast;
    int i = blockIdx.x * SCAN_BLK + threadIdx.x;
    int v = (i < N) ? cnt[i] : 0;
    if (i < N) {
        float dv = rsqrtf((float)v + 1.0f);
        dinv[i] = dv;
        float2 xv = ((const float2*)x)[i];
        y[i] = make_float2(xv.x * dv, xv.y * dv);
    }
    sm[threadIdx.x] = v;
    __syncthreads();
    for (int off = 1; off < SCAN_BLK; off <<= 1) {
        int t = (threadIdx.x >= (unsigned)off) ? sm[threadIdx.x - off] : 0;
        __syncthreads();
        sm[threadIdx.x] += t;
        __syncthreads();
    }
    if (i < N) row_ptr[i] = sm[threadIdx.x] - v;
    if (threadIdx.x == SCAN_BLK - 1) bsum[blockIdx.x] = sm[SCAN_BLK - 1];
    __syncthreads();                       // all block stores issued & drained
    if (threadIdx.x == 0) {
        __threadfence();                   // publish this block's stores device-wide
        amLast = (atomicAdd(ticket, 1) == (int)gridDim.x - 1);
    }
    __syncthreads();
    if (!amLast) return;
    // closer block: exclusive-scan the block sums (coherent atomic reads), compute goff
    int nb = (int)gridDim.x;
    int v2 = (threadIdx.x < (unsigned)nb) ? atomicAdd(&bsum[threadIdx.x], 0) : 0;
    sm[threadIdx.x] = v2;
    __syncthreads();
    for (int off = 1; off < SCAN_BLK; off <<= 1) {
        int t = (threadIdx.x >= (unsigned)off) ? sm[threadIdx.x - off] : 0;
        __syncthreads();
        sm[threadIdx.x] += t;
        __syncthreads();
    }
    if (threadIdx.x < (unsigned)nb) bsum[threadIdx.x] = sm[threadIdx.x] - v2;
    if (threadIdx.x <= NGRAPH) {
        int g = threadIdx.x;
        int lo = 0, hi = N;
        while (lo < hi) {
            int mid = (lo + hi) >> 1;
            if (batch[mid] < g) lo = mid + 1; else hi = mid;
        }
        goff[g] = lo;
    }
}

// fill via precomputed rank: pure scattered write, no atomics
__global__ void fill_kernel(const int* __restrict__ src, const int* __restrict__ dst, int E,
                            const int* __restrict__ row_ptr, const int* __restrict__ bsum,
                            const int* __restrict__ rank, int* __restrict__ col) {
    int e = blockIdx.x * blockDim.x + threadIdx.x;
    if (e < E) {
        int d = dst[e];
        int p = row_ptr[d] + bsum[d >> 10] + rank[e];
        col[p] = src[e];
    }
}

// ---------------- layer 1 fused: z = agg(y) ; h1 = tanh(z @ W1 + b1) (bf16, quarter-major out) --------
// 4 lanes per node (64 nodes / 256-thread block) for latency hiding; shfl width-4 reduce.

__global__ __launch_bounds__(256) void agg_x_t1(const float2* __restrict__ y,
                                                const int* __restrict__ row_ptr,
                                                const int* __restrict__ bsum,
                                                const int* __restrict__ col,
                                                const float* __restrict__ dinv,
                                                const float* __restrict__ W1,
                                                const float* __restrict__ b1,
                                                unsigned short* __restrict__ h, int N, int E) {
    __shared__ float4 sW[64];     // W1[2][128]
    __shared__ float4 sb[32];     // b1[128]
    __shared__ float2 zs[64];
    __shared__ int scol[AXCAP];
    if (threadIdx.x < 64) sW[threadIdx.x] = ((const float4*)W1)[threadIdx.x];
    if (threadIdx.x >= 64 && threadIdx.x < 96) sb[threadIdx.x - 64] = ((const float4*)b1)[threadIdx.x - 64];

    int firstNode = blockIdx.x * 64;
    int lastNode = min(firstNode + 64, N);
    int sBase = row_ptr[firstNode] + bsum[firstNode >> 10];
    int eEnd = (lastNode < N) ? row_ptr[lastNode] + bsum[lastNode >> 10] : E;
    int range = eEnd - sBase;
    bool inLds = (range <= AXCAP);
    if (inLds) {
        for (int i = threadIdx.x; i < range; i += 256) scol[i] = col[sBase + i];
    }
    __syncthreads();

    int grp = threadIdx.x >> 2;        // node slot 0..63
    int l4 = threadIdx.x & 3;
    int node = firstNode + grp;
    float ax = 0.f, ay = 0.f;
    if (node < N) {
        int s = row_ptr[node] + bsum[node >> 10];
        int e = (node + 1 < N) ? row_ptr[node + 1] + bsum[(node + 1) >> 10] : E;
        int deg = e - s;
        if (inLds) {
            int sl = s - sBase;
            int j = l4;
            for (; j + 4 < deg; j += 8) {
                float2 v0 = y[scol[sl + j]];
                float2 v1 = y[scol[sl + j + 4]];
                ax += v0.x; ay += v0.y;
                ax += v1.x; ay += v1.y;
            }
            if (j < deg) { float2 v = y[scol[sl + j]]; ax += v.x; ay += v.y; }
        } else {
            int j = l4;
            for (; j + 4 < deg; j += 8) {
                float2 v0 = y[col[s + j]];
                float2 v1 = y[col[s + j + 4]];
                ax += v0.x; ay += v0.y;
                ax += v1.x; ay += v1.y;
            }
            if (j < deg) { float2 v = y[col[s + j]]; ax += v.x; ay += v.y; }
        }
    }
    ax += __shfl_xor(ax, 1, 64); ay += __shfl_xor(ay, 1, 64);
    ax += __shfl_xor(ax, 2, 64); ay += __shfl_xor(ay, 2, 64);
    if (l4 == 0 && node < N) {
        float2 self = y[node];
        float dv = dinv[node];
        zs[grp] = make_float2(dv * (ax + self.x), dv * (ay + self.y));
    }
    __syncthreads();

    int q = threadIdx.x & 31;          // col quad (4 cols)
    int rsub = threadIdx.x >> 5;       // 0..7
    float4 w0 = sW[q];
    float4 w1 = sW[32 + q];
    float4 b = sb[q];
    size_t qoff = (size_t)(q >> 3) * N;  // quarter base (rows)
#pragma unroll
    for (int pass = 0; pass < 8; ++pass) {
        int local = pass * 8 + rsub;
        int row = firstNode + local;
        if (row >= N) break;
        float2 z = zs[local];
        float ox = tanhf(fmaf(z.x, w0.x, fmaf(z.y, w1.x, b.x)));
        float oy = tanhf(fmaf(z.x, w0.y, fmaf(z.y, w1.y, b.y)));
        float oz = tanhf(fmaf(z.x, w0.z, fmaf(z.y, w1.z, b.z)));
        float ow = tanhf(fmaf(z.x, w0.w, fmaf(z.y, w1.w, b.w)));
        uint2 pk;
        pk.x = pack_bf16x2(ox, oy);
        pk.y = pack_bf16x2(oz, ow);
        ((uint2*)h)[(qoff + row) * 8 + (q & 7)] = pk;
    }
}

// ---------------- MFMA GEMM: t[4][N][32](bf16) = (A[4][N][32](bf16) @ W) * dinv ----------------
// Operands SWAPPED vs naive: mfma(W_frag, A_frag, acc) computes the transposed fragment, so
// lane&15 indexes the NODE and reg 0..3 indexes 4 consecutive features -> 8B uint2 stores.

__global__ __launch_bounds__(256) void gemm_mfma(const unsigned short* __restrict__ A,
                                                 const unsigned* __restrict__ Wt,
                                                 const float* __restrict__ dinv,
                                                 unsigned short* __restrict__ t, int N) {
    __shared__ unsigned sW[128 * 68];
    const uint4* Wt4 = (const uint4*)Wt;
    for (int i = threadIdx.x; i < 2048; i += 256) {
        int n = i >> 4, c = i & 15;
        *(uint4*)&sW[n * 68 + c * 4] = Wt4[i];
    }
    __syncthreads();
    int l = threadIdx.x & 63;
    int w = threadIdx.x >> 6;
    int lm = l & 15;
    int q4 = l >> 4;

    floatx4 acc[2][8];
#pragma unroll
    for (int i = 0; i < 2; ++i)
#pragma unroll
        for (int j = 0; j < 8; ++j) acc[i][j] = (floatx4){0.f, 0.f, 0.f, 0.f};

    int rowbase = blockIdx.x * 128 + w * 32;
    int k8 = q4 * 8;
#pragma unroll
    for (int ks = 0; ks < 4; ++ks) {
        short8 a[2];
#pragma unroll
        for (int mt = 0; mt < 2; ++mt) {
            int r = min(rowbase + mt * 16 + lm, N - 1);
            a[mt] = *(const short8*)(A + ((size_t)ks * N + r) * 32 + k8);
        }
#pragma unroll
        for (int nt = 0; nt < 8; ++nt) {
            short8 b = *(const short8*)&sW[(nt * 16 + lm) * 68 + ks * 16 + q4 * 4];
#pragma unroll
            for (int mt = 0; mt < 2; ++mt)
                acc[mt][nt] = __builtin_amdgcn_mfma_f32_16x16x32_bf16(b, a[mt], acc[mt][nt], 0, 0, 0);
        }
    }

#pragma unroll
    for (int mt = 0; mt < 2; ++mt) {
        int gr = rowbase + mt * 16 + lm;
        if (gr < N) {
            float dv = dinv[gr];
#pragma unroll
            for (int nt = 0; nt < 8; ++nt) {
                uint2 pk;
                pk.x = pack_bf16x2(acc[mt][nt][0] * dv, acc[mt][nt][1] * dv);
                pk.y = pack_bf16x2(acc[mt][nt][2] * dv, acc[mt][nt][3] * dv);
                *(uint2*)(t + ((size_t)(nt >> 1) * N + gr) * 32 + (nt & 1) * 16 + q4 * 4) = pk;
            }
        }
    }
}

// ---------------- layer-2 aggregation: 256 nodes/block (1024 thr), 4 lanes/node -------------
// XCD-affinity swizzle + LDS-staged col slice + masked 4-wide tail.

__global__ __launch_bounds__(1024) void agg_kernel(const unsigned short* __restrict__ t,
                                                   const int* __restrict__ row_ptr,
                                                   const int* __restrict__ bsum,
                                                   const int* __restrict__ col,
                                                   const float* __restrict__ dinv,
                                                   const float* __restrict__ bias,
                                                   unsigned short* __restrict__ out, int N, int E) {
    int nchunk = (N + 255) >> 8;
    int bid = (int)blockIdx.x;
    int r8 = bid & 7;
    int qt = r8 >> 1;                              // feature quarter 0..3 (XCD pair)
    int c = (bid >> 3) * 2 + (r8 & 1);             // node chunk
    if (c >= nchunk) return;

    __shared__ int scol[COLCAP];
    int firstNode = c * 256;
    int lastNode = min(firstNode + 256, N);
    int sBase = row_ptr[firstNode] + bsum[firstNode >> 10];
    int eEnd = (lastNode < N) ? row_ptr[lastNode] + bsum[lastNode >> 10] : E;
    int range = eEnd - sBase;
    bool inLds = (range <= COLCAP);
    if (inLds) {
        for (int i = threadIdx.x; i < range; i += 1024) scol[i] = col[sBase + i];
    }
    __syncthreads();

    int q = threadIdx.x & 3;                       // 16B col slot (8 bf16)
    int node = firstNode + ((int)threadIdx.x >> 2);
    if (node >= N) return;
    const uint4* t4 = (const uint4*)t;
    unsigned qb = (unsigned)qt * (unsigned)N;
    int s = row_ptr[node] + bsum[node >> 10];
    int e = (node + 1 < N) ? row_ptr[node + 1] + bsum[(node + 1) >> 10] : E;
    int deg = e - s;

    float a[8];
    {   // self term
        uint4 v = t4[TIDX(node)];
        a[0] = bf16lo(v.x); a[1] = bf16hi(v.x);
        a[2] = bf16lo(v.y); a[3] = bf16hi(v.y);
        a[4] = bf16lo(v.z); a[5] = bf16hi(v.z);
        a[6] = bf16lo(v.w); a[7] = bf16hi(v.w);
    }
    int j = 0;
    if (inLds) {
        int sl = s - sBase;
        for (; j + 4 <= deg; j += 4) {
            int u0 = scol[sl + j], u1 = scol[sl + j + 1];
            int u2 = scol[sl + j + 2], u3 = scol[sl + j + 3];
            ACC4();
        }
        if (j < deg) {
            float m1 = (j + 1 < deg) ? 1.f : 0.f;
            float m2 = (j + 2 < deg) ? 1.f : 0.f;
            float m3 = (j + 3 < deg) ? 1.f : 0.f;
            int u0 = scol[sl + j];
            int u1 = scol[sl + min(j + 1, deg - 1)];
            int u2 = scol[sl + min(j + 2, deg - 1)];
            int u3 = scol[sl + min(j + 3, deg - 1)];
            ACC4M();
        }
    } else {
        for (; j + 4 <= deg; j += 4) {
            int u0 = col[s + j], u1 = col[s + j + 1];
            int u2 = col[s + j + 2], u3 = col[s + j + 3];
            ACC4();
        }
        if (j < deg) {
            float m1 = (j + 1 < deg) ? 1.f : 0.f;
            float m2 = (j + 2 < deg) ? 1.f : 0.f;
            float m3 = (j + 3 < deg) ? 1.f : 0.f;
            int u0 = col[s + j];
            int u1 = col[s + min(j + 1, deg - 1)];
            int u2 = col[s + min(j + 2, deg - 1)];
            int u3 = col[s + min(j + 3, deg - 1)];
            ACC4M();
        }
    }

    float dv = dinv[node];
    const float4* b4 = (const float4*)bias;
    float4 b0 = b4[qt * 8 + q * 2];
    float4 b1 = b4[qt * 8 + q * 2 + 1];
    uint4 pk;
    pk.x = pack_bf16x2(tanhf(fmaf(dv, a[0], b0.x)), tanhf(fmaf(dv, a[1], b0.y)));
    pk.y = pack_bf16x2(tanhf(fmaf(dv, a[2], b0.z)), tanhf(fmaf(dv, a[3], b0.w)));
    pk.z = pack_bf16x2(tanhf(fmaf(dv, a[4], b1.x)), tanhf(fmaf(dv, a[5], b1.y)));
    pk.w = pack_bf16x2(tanhf(fmaf(dv, a[6], b1.z)), tanhf(fmaf(dv, a[7], b1.w)));
    ((uint4*)out)[TIDX(node)] = pk;
}

// ---------------- layer-3 aggregation + FUSED pooling (h3 never materialized) ----------------

__global__ __launch_bounds__(1024) void agg3_pool(const unsigned short* __restrict__ t,
                                                  const int* __restrict__ row_ptr,
                                                  const int* __restrict__ bsum,
                                                  const int* __restrict__ col,
                                                  const float* __restrict__ dinv,
                                                  const float* __restrict__ bias,
                                                  const int* __restrict__ batch,
                                                  unsigned* __restrict__ pmax,
                                                  float* __restrict__ psum, int N, int E) {
    int nchunk = (N + 255) >> 8;
    int bid = (int)blockIdx.x;
    int r8 = bid & 7;
    int qt = r8 >> 1;
    int c = (bid >> 3) * 2 + (r8 & 1);
    if (c >= nchunk) return;

    __shared__ unsigned smax[2][32];
    __shared__ float ssum[2][32];
    __shared__ int scol[COLCAP];
    if (threadIdx.x < 64) {
        smax[threadIdx.x >> 5][threadIdx.x & 31] = 0u;
        ssum[threadIdx.x >> 5][threadIdx.x & 31] = 0.f;
    }
    int firstNode = c * 256;
    int lastNode = min(firstNode + 256, N);
    int sBase = row_ptr[firstNode] + bsum[firstNode >> 10];
    int eEnd = (lastNode < N) ? row_ptr[lastNode] + bsum[lastNode >> 10] : E;
    int range = eEnd - sBase;
    bool inLds = (range <= COLCAP);
    if (inLds) {
        for (int i = threadIdx.x; i < range; i += 1024) scol[i] = col[sBase + i];
    }
    __syncthreads();

    int q = threadIdx.x & 3;
    int blockBase = firstNode;
    int node = blockBase + ((int)threadIdx.x >> 2);
    bool valid = node < N;
    int nc = valid ? node : N - 1;
    const uint4* t4 = (const uint4*)t;
    unsigned qb = (unsigned)qt * (unsigned)N;
    int s = row_ptr[nc] + bsum[nc >> 10];
    int e = (nc + 1 < N) ? row_ptr[nc + 1] + bsum[(nc + 1) >> 10] : E;
    int deg = valid ? (e - s) : 0;

    float a[8];
    {   // self term (of nc; discarded for invalid lanes)
        uint4 v = t4[TIDX(nc)];
        a[0] = bf16lo(v.x); a[1] = bf16hi(v.x);
        a[2] = bf16lo(v.y); a[3] = bf16hi(v.y);
        a[4] = bf16lo(v.z); a[5] = bf16hi(v.z);
        a[6] = bf16lo(v.w); a[7] = bf16hi(v.w);
    }
    int j = 0;
    if (inLds) {
        int sl = s - sBase;
        for (; j + 4 <= deg; j += 4) {
            int u0 = scol[sl + j], u1 = scol[sl + j + 1];
            int u2 = scol[sl + j + 2], u3 = scol[sl + j + 3];
            ACC4();
        }
        if (j < deg) {
            float m1 = (j + 1 < deg) ? 1.f : 0.f;
            float m2 = (j + 2 < deg) ? 1.f : 0.f;
            float m3 = (j + 3 < deg) ? 1.f : 0.f;
            int u0 = scol[sl + j];
            int u1 = scol[sl + min(j + 1, deg - 1)];
            int u2 = scol[sl + min(j + 2, deg - 1)];
            int u3 = scol[sl + min(j + 3, deg - 1)];
            ACC4M();
        }
    } else {
        for (; j + 4 <= deg; j += 4) {
            int u0 = col[s + j], u1 = col[s + j + 1];
            int u2 = col[s + j + 2], u3 = col[s + j + 3];
            ACC4();
        }
        if (j < deg) {
            float m1 = (j + 1 < deg) ? 1.f : 0.f;
            float m2 = (j + 2 < deg) ? 1.f : 0.f;
            float m3 = (j + 3 < deg) ? 1.f : 0.f;
            int u0 = col[s + j];
            int u1 = col[s + min(j + 1, deg - 1)];
            int u2 = col[s + min(j + 2, deg - 1)];
            int u3 = col[s + min(j + 3, deg - 1)];
            ACC4M();
        }
    }

    float dv = dinv[nc];
    const float4* b4 = (const float4*)bias;
    float4 b0 = b4[qt * 8 + q * 2];
    float4 b1 = b4[qt * 8 + q * 2 + 1];
    float o[8];
    o[0] = tanhf(fmaf(dv, a[0], b0.x)); o[1] = tanhf(fmaf(dv, a[1], b0.y));
    o[2] = tanhf(fmaf(dv, a[2], b0.z)); o[3] = tanhf(fmaf(dv, a[3], b0.w));
    o[4] = tanhf(fmaf(dv, a[4], b1.x)); o[5] = tanhf(fmaf(dv, a[5], b1.y));
    o[6] = tanhf(fmaf(dv, a[6], b1.z)); o[7] = tanhf(fmaf(dv, a[7], b1.w));

    int g = batch[nc];
    int g0 = batch[min(blockBase, N - 1)];
    int gl = __shfl(g, 0, 64);
    int gh = __shfl(g, 63, 64);

    if (gl == gh) {
        float m[8], sv[8];
#pragma unroll
        for (int k = 0; k < 8; ++k) {
            m[k] = valid ? o[k] : -3.402823466e+38f;
            sv[k] = valid ? o[k] : 0.f;
        }
#pragma unroll
        for (int st = 4; st < 64; st <<= 1) {
#pragma unroll
            for (int k = 0; k < 8; ++k) {
                m[k] = fmaxf(m[k], __shfl_xor(m[k], st, 64));
                sv[k] += __shfl_xor(sv[k], st, 64);
            }
        }
        if (((threadIdx.x & 63) >> 2) == 0) {
            int seg = gl - g0;
            if (seg < 2) {
#pragma unroll
                for (int k = 0; k < 8; ++k) {
                    atomicMax(&smax[seg][q * 8 + k], fkey(m[k]));
                    atomicAdd(&ssum[seg][q * 8 + k], sv[k]);
                }
            } else {
#pragma unroll
                for (int k = 0; k < 8; ++k) {
                    atomicMax(&pmax[gl * 128 + qt * 32 + q * 8 + k], fkey(m[k]));
                    atomicAdd(&psum[gl * 128 + qt * 32 + q * 8 + k], sv[k]);
                }
            }
        }
    } else {
        if (valid) {
            int seg = g - g0;
            if (seg < 2) {
#pragma unroll
                for (int k = 0; k < 8; ++k) {
                    atomicMax(&smax[seg][q * 8 + k], fkey(o[k]));
                    atomicAdd(&ssum[seg][q * 8 + k], o[k]);
                }
            } else {
#pragma unroll
                for (int k = 0; k < 8; ++k) {
                    atomicMax(&pmax[g * 128 + qt * 32 + q * 8 + k], fkey(o[k]));
                    atomicAdd(&psum[g * 128 + qt * 32 + q * 8 + k], o[k]);
                }
            }
        }
    }
    __syncthreads();
    if (threadIdx.x < 64) {
        int seg = threadIdx.x >> 5, cc = threadIdx.x & 31;
        int g0b = batch[min(blockBase, N - 1)];
        int gg = g0b + seg;
        if (gg < NGRAPH) {
            atomicMax(&pmax[gg * 128 + qt * 32 + cc], smax[seg][cc]);
            atomicAdd(&psum[gg * 128 + qt * 32 + cc], ssum[seg][cc]);
        }
    }
}

// ---------------- final: decode pooled accumulators + output head ----------------

__global__ __launch_bounds__(128) void pool_final(const unsigned* __restrict__ pmax,
                                                  const float* __restrict__ psum,
                                                  const int* __restrict__ goff,
                                                  const float* __restrict__ Wo,
                                                  const float* __restrict__ bo,
                                                  float* __restrict__ out) {
    __shared__ float p[256];
    int g = blockIdx.x;
    int j = threadIdx.x;
    int cnt = goff[g + 1] - goff[g];
    unsigned key = pmax[g * 128 + j];
    float mx = (key & 0x80000000u) ? __uint_as_float(key ^ 0x80000000u)
                                   : __uint_as_float(~key);
    p[j] = (cnt > 0) ? mx : 0.f;
    p[128 + j] = psum[g * 128 + j] / fmaxf((float)cnt, 1.f);
    __syncthreads();
    if (j < 41) {
        float acc = bo[j];
        for (int k = 0; k < 256; ++k) acc = fmaf(p[k], Wo[k * 41 + j], acc);
        out[g * 41 + j] = tanhf(acc);
    }
}

// ---------------- launch ----------------

extern "C" void kernel_launch(void* const* d_in, const int* in_sizes, int n_in,
                              void* d_out, int out_size, void* d_ws, size_t ws_size,
                              hipStream_t stream) {
    const float* x   = (const float*)d_in[0];
    const int*   ei  = (const int*)d_in[1];
    const int* batch = (const int*)d_in[2];
    const float* W1  = (const float*)d_in[3];
    const float* b1  = (const float*)d_in[4];
    const float* W2  = (const float*)d_in[5];
    const float* b2  = (const float*)d_in[6];
    const float* W3  = (const float*)d_in[7];
    const float* b3  = (const float*)d_in[8];
    const float* Wo  = (const float*)d_in[9];
    const float* bo  = (const float*)d_in[10];
    float* outp = (float*)d_out;

    int N = in_sizes[2];
    int E = in_sizes[1] / 2;
    const int* src = ei;
    const int* dst = ei + E;

    char* p = (char*)d_ws;
    auto alloc = [&](size_t bytes) -> char* {
        char* q = p;
        p += (bytes + 255) & ~(size_t)255;
        return q;
    };
    unsigned short* t   = (unsigned short*)alloc((size_t)N * 128 * 2);  // bf16 gemm out [4][N][32]
    unsigned short* hb  = (unsigned short*)alloc((size_t)N * 128 * 2);  // bf16 h1 / h2  [4][N][32]
    float* dinv   = (float*)alloc((size_t)N * 4);
    int*   rowp   = (int*)alloc((size_t)(N + 1) * 4);
    int*   col    = (int*)alloc((size_t)E * 4);
    int*   rank   = (int*)alloc((size_t)E * 4);
    int*   goff   = (int*)alloc(65 * 4);
    float2* y     = (float2*)alloc((size_t)N * 8);
    unsigned* Wt2 = (unsigned*)alloc(128 * 64 * 4);
    unsigned* Wt3 = (unsigned*)alloc(128 * 64 * 4);
    int nscan = (N + SCAN_BLK - 1) / SCAN_BLK;
    int*   bsum   = (int*)alloc((size_t)nscan * 4);
    // zero-init region: cnt | ticket | pmax | psum (single memset)
    size_t cntB = ((size_t)N * 4 + 255) & ~(size_t)255;
    char* zbase = alloc(cntB + 256 + NGRAPH * 128 * 4 * 2);
    int*      cnt  = (int*)zbase;
    int*      tick = (int*)(zbase + cntB);
    unsigned* pmax = (unsigned*)(zbase + cntB + 256);
    float*    psum = (float*)(zbase + cntB + 256 + NGRAPH * 128 * 4);

    (void)hipMemsetAsync(zbase, 0, cntB + 256 + NGRAPH * 128 * 4 * 2, stream);

    pack_count<<<32 + (E + 255) / 256, 256, 0, stream>>>(dst, E, cnt, rank, W2, W3, Wt2, Wt3);
    scanA<<<nscan, SCAN_BLK, 0, stream>>>(cnt, x, rowp, bsum, dinv, y, batch, tick, goff, N);
    fill_kernel<<<(E + 255) / 256, 256, 0, stream>>>(src, dst, E, rowp, bsum, rank, col);

    // agg grid: XCD-affinity swizzled flat grid (see agg_kernel)
    int nchunk = (N + 255) >> 8;
    int nchunkR = (nchunk + 1) & ~1;         // round up to even
    int nblk = nchunkR * 4;                  // = (nchunkR/2) * 8, multiple of 8

    // layer 1: fused agg(x) + transform -> h1 (bf16, quarter-major); 4 lanes/node
    agg_x_t1<<<(N + 63) / 64, 256, 0, stream>>>(y, rowp, bsum, col, dinv, W1, b1, hb, N, E);
    // layer 2
    gemm_mfma<<<(N + 127) / 128, 256, 0, stream>>>(hb, Wt2, dinv, t, N);
    agg_kernel<<<nblk, 1024, 0, stream>>>(t, rowp, bsum, col, dinv, b2, hb, N, E);
    // layer 3 (pooling fused into agg)
    gemm_mfma<<<(N + 127) / 128, 256, 0, stream>>>(hb, Wt3, dinv, t, N);
    agg3_pool<<<nblk, 1024, 0, stream>>>(t, rowp, bsum, col, dinv, b3, batch, pmax, psum, N, E);

    pool_final<<<NGRAPH, 128, 0, stream>>>(pmax, psum, goff, Wo, bo, outp);
}